// Round 9
// baseline (329.510 us; speedup 1.0000x reference)
//
#include <hip/hip_runtime.h>
#include <hip/hip_bf16.h>
#include <math.h>

// Problem constants
#define NPIX 9216   // 96*96
#define HDIM 96
#define WDIM 96
#define NHEADS 6
#define BATCH 4

typedef __bf16 bf16x8 __attribute__((ext_vector_type(8)));
typedef _Float16 f16x8 __attribute__((ext_vector_type(8)));
typedef float  f32x4  __attribute__((ext_vector_type(4)));

struct Bias6 { const float* p[6]; };

// async global->LDS 16B copy (dest must be wave-uniform-base + lane*16)
__device__ __forceinline__ void cp16(void* ldst, const void* gsrc) {
    __builtin_amdgcn_global_load_lds(
        (const __attribute__((address_space(1))) unsigned int*)gsrc,
        (__attribute__((address_space(3))) unsigned int*)ldst, 16, 0, 0);
}

__device__ __forceinline__ unsigned short bfbits(__bf16 x) { return *(unsigned short*)&x; }

// ---------------------------------------------------------------------------
// Weight conversion: fp32 -> bf16 hi/lo (both weight matrices in one launch)
// ---------------------------------------------------------------------------
__global__ __launch_bounds__(256) void convert_w(
    const float* __restrict__ w1, __bf16* __restrict__ h1, __bf16* __restrict__ l1, int n1,
    const float* __restrict__ w2, __bf16* __restrict__ h2, __bf16* __restrict__ l2, int n2)
{
    const int i = blockIdx.x * 256 + threadIdx.x;
    if (i < n1) { float f = w1[i]; __bf16 h = (__bf16)f; h1[i] = h; l1[i] = (__bf16)(f - (float)h); }
    if (i < n2) { float f = w2[i]; __bf16 h = (__bf16)f; h2[i] = h; l2[i] = (__bf16)(f - (float)h); }
}

// ---------------------------------------------------------------------------
// x transpose+convert: [B][192][NPIX] fp32 -> records [B][NPIX][192] bf16 (hi)
// ---------------------------------------------------------------------------
__global__ __launch_bounds__(256) void convert_x(
    const float* __restrict__ x, __bf16* __restrict__ Xh)
{
    __shared__ float t[32][65];
    const int b  = blockIdx.z;
    const int c0 = blockIdx.y * 32;
    const int p0 = blockIdx.x * 64;
    const int tid = threadIdx.x;
    const int pl = tid & 63;
    #pragma unroll
    for (int i = 0; i < 8; ++i) {
        const int c = i * 4 + (tid >> 6);
        t[c][pl] = x[((size_t)b * 192 + c0 + c) * NPIX + p0 + pl];
    }
    __syncthreads();
    const int p  = tid >> 2;
    const int cq = (tid & 3) * 8;
    bf16x8 vh;
    #pragma unroll
    for (int j = 0; j < 8; ++j)
        vh[j] = (__bf16)t[cq + j][p];
    *(bf16x8*)(Xh + ((size_t)b * NPIX + p0 + p) * 192 + c0 + cq) = vh;
}

// ---------------------------------------------------------------------------
// bf16 MFMA GEMM (2-product, weights exact): Y[b][m][n] = sum_k W[m][k]*X[b][n][k]
// m97 structure: BM=64 BN=128 BK=64; global_load_lds staging + chunk-XOR swizzle.
// OutT = _Float16 (qkv planes) or float (final output planes).
// ---------------------------------------------------------------------------
template<typename OutT>
__global__ __launch_bounds__(256) void gemm_mfma(
    const __bf16* __restrict__ Ah, const __bf16* __restrict__ Al,
    const __bf16* __restrict__ Bh,
    OutT* __restrict__ Y, int M)
{
    __shared__ __bf16 sAh[64 * 64];    // [row][64ch], 8 KB, chunk-swizzled
    __shared__ __bf16 sAl[64 * 64];
    __shared__ __bf16 sBh[128 * 64];   // 16 KB

    const int b  = blockIdx.z;
    const int n0 = blockIdx.x * 128;
    const int m0 = blockIdx.y * 64;
    const int tid  = threadIdx.x;
    const int lane = tid & 63;
    const int wid  = tid >> 6;
    const int wr = wid >> 1, wc = wid & 1;
    const int lr = lane & 15;
    const int kg = lane >> 4;

    const char* gA_h = (const char*)Ah + (size_t)m0 * 384;
    const char* gA_l = (const char*)Al + (size_t)m0 * 384;
    const char* gB   = (const char*)Bh + ((size_t)b * NPIX + n0) * 384;

    f32x4 acc[2][4];
    #pragma unroll
    for (int mf = 0; mf < 2; ++mf)
        #pragma unroll
        for (int nf = 0; nf < 4; ++nf)
            acc[mf][nf] = (f32x4){0.f, 0.f, 0.f, 0.f};

    for (int ks = 0; ks < 3; ++ks) {
        if (ks) __syncthreads();
        const int kb = ks * 128;              // byte offset of k-step in a row
        #pragma unroll
        for (int it = 0; it < 2; ++it) {
            const int d  = it * 256 + tid;    // 0..511
            const int rd = d >> 3, cd = d & 7;
            const size_t src = (size_t)rd * 384 + kb + ((cd ^ (rd & 7)) << 4);
            cp16((char*)sAh + d * 16, gA_h + src);
            cp16((char*)sAl + d * 16, gA_l + src);
        }
        #pragma unroll
        for (int it = 0; it < 4; ++it) {
            const int d  = it * 256 + tid;    // 0..1023
            const int rd = d >> 3, cd = d & 7;
            const size_t src = (size_t)rd * 384 + kb + ((cd ^ (rd & 7)) << 4);
            cp16((char*)sBh + d * 16, gB + src);
        }
        __syncthreads();    // drains vmcnt for the async LDS writes
        #pragma unroll
        for (int s = 0; s < 2; ++s) {
            bf16x8 aH[2], aL[2], bH[4];
            #pragma unroll
            for (int mf = 0; mf < 2; ++mf) {
                const int row = wr * 32 + mf * 16 + lr;
                const int c = (s * 4 + kg) ^ (row & 7);
                aH[mf] = *(const bf16x8*)((const char*)sAh + row * 128 + c * 16);
                aL[mf] = *(const bf16x8*)((const char*)sAl + row * 128 + c * 16);
            }
            #pragma unroll
            for (int nf = 0; nf < 4; ++nf) {
                const int row = wc * 64 + nf * 16 + lr;
                const int c = (s * 4 + kg) ^ (row & 7);
                bH[nf] = *(const bf16x8*)((const char*)sBh + row * 128 + c * 16);
            }
            #pragma unroll
            for (int mf = 0; mf < 2; ++mf)
                #pragma unroll
                for (int nf = 0; nf < 4; ++nf) {
                    acc[mf][nf] = __builtin_amdgcn_mfma_f32_16x16x32_bf16(aH[mf], bH[nf], acc[mf][nf], 0, 0, 0);
                    acc[mf][nf] = __builtin_amdgcn_mfma_f32_16x16x32_bf16(aL[mf], bH[nf], acc[mf][nf], 0, 0, 0);
                }
        }
    }

    // D layout: col = lane&15, row = (lane>>4)*4 + r
    OutT* Yb = Y + ((size_t)b * M + m0 + wr * 32) * NPIX + n0 + wc * 64;
    #pragma unroll
    for (int mf = 0; mf < 2; ++mf)
        #pragma unroll
        for (int r = 0; r < 4; ++r) {
            const int row = mf * 16 + kg * 4 + r;
            #pragma unroll
            for (int nf = 0; nf < 4; ++nf)
                Yb[(size_t)row * NPIX + nf * 16 + lr] = (OutT)acc[mf][nf][r];
        }
}

// ---------------------------------------------------------------------------
// LDS-tiled neighborhood attention, f16 planes, 8 channels per round.
// Inner loops use (float)h * f patterns -> v_fma_mix_f32 (no unpack ops).
// qkv planes f16 [B][576][NPIX]; output bf16 records [B][NPIX][192] via
// 8KB LDS transpose tile, two half-record write batches.
// ---------------------------------------------------------------------------
#define MAX_REGION 1300   // head (7,3): (8+18) x (32+18)

template<int KSZ, int DIL>
__device__ __forceinline__ void attn_body(
    const unsigned short* __restrict__ Qs, const unsigned short* __restrict__ Ks,
    const unsigned short* __restrict__ Vs, const float* __restrict__ bias,
    __bf16* __restrict__ oh, int h0, int w0,
    uint4* __restrict__ lds,
    unsigned (* __restrict__ out_lds)[256])
{
    constexpr int CC  = KSZ / 2;
    constexpr int HAL = CC * DIL;
    constexpr int R   = 8 + 2 * HAL;
    constexpr int C   = 32 + 2 * HAL;
    constexpr int RC  = R * C;
    constexpr int NN  = KSZ * KSZ;
    const float scale = 0.17677669529663689f;   // 1/sqrt(32)

    const int tx = threadIdx.x & 31;
    const int ty = threadIdx.x >> 5;
    const int pix = (h0 + ty) * WDIM + (w0 + tx);
    const int lb = ty * C + tx;

    float score[NN];
    #pragma unroll
    for (int n = 0; n < NN; ++n) score[n] = 0.f;

    // ---- phase 1: scores (4 rounds of 8 channels) ----
    for (int ch = 0; ch < 32; ch += 8) {
        __syncthreads();
        for (int idx = threadIdx.x; idx < RC; idx += 256) {
            const int r = idx / C, c = idx - r * C;
            const int gh = h0 - HAL + r, gw = w0 - HAL + c;
            uint4 v = make_uint4(0u, 0u, 0u, 0u);
            if ((unsigned)gh < (unsigned)HDIM && (unsigned)gw < (unsigned)WDIM) {
                const unsigned short* p = Ks + (size_t)ch * NPIX + gh * WDIM + gw;
                v.x = (unsigned)p[0 * NPIX] | ((unsigned)p[1 * NPIX] << 16);
                v.y = (unsigned)p[2 * NPIX] | ((unsigned)p[3 * NPIX] << 16);
                v.z = (unsigned)p[4 * NPIX] | ((unsigned)p[5 * NPIX] << 16);
                v.w = (unsigned)p[6 * NPIX] | ((unsigned)p[7 * NPIX] << 16);
            }
            lds[idx] = v;
        }
        __syncthreads();
        float q[8];
        #pragma unroll
        for (int j = 0; j < 8; ++j)
            q[j] = (float)((const _Float16*)Qs)[(size_t)(ch + j) * NPIX + pix];
        #pragma unroll
        for (int i = 0; i < KSZ; ++i)
            #pragma unroll
            for (int j = 0; j < KSZ; ++j) {
                const f16x8 k8 = *(const f16x8*)&lds[lb + i * DIL * C + j * DIL];
                float s = score[i * KSZ + j];
                #pragma unroll
                for (int d = 0; d < 8; ++d)
                    s += q[d] * (float)k8[d];          // v_fma_mix_f32
                score[i * KSZ + j] = s;
            }
    }

    // ---- softmax (no max-shift: |scores| < 1 for this distribution) ----
    float l = 0.f;
    #pragma unroll
    for (int n = 0; n < NN; ++n) {
        const float e = __expf(score[n] * scale + bias[n]);
        l += e;
        score[n] = e;
    }
    const float inv = 1.f / l;

    // ---- phase 2: PV (two halves of 16 channels; 8KB out tile each) ----
    #pragma unroll
    for (int half = 0; half < 2; ++half) {
        #pragma unroll
        for (int rr = 0; rr < 2; ++rr) {
            const int ch = half * 16 + rr * 8;
            __syncthreads();
            for (int idx = threadIdx.x; idx < RC; idx += 256) {
                const int r = idx / C, c = idx - r * C;
                const int gh = h0 - HAL + r, gw = w0 - HAL + c;
                uint4 v = make_uint4(0u, 0u, 0u, 0u);
                if ((unsigned)gh < (unsigned)HDIM && (unsigned)gw < (unsigned)WDIM) {
                    const unsigned short* p = Vs + (size_t)ch * NPIX + gh * WDIM + gw;
                    v.x = (unsigned)p[0 * NPIX] | ((unsigned)p[1 * NPIX] << 16);
                    v.y = (unsigned)p[2 * NPIX] | ((unsigned)p[3 * NPIX] << 16);
                    v.z = (unsigned)p[4 * NPIX] | ((unsigned)p[5 * NPIX] << 16);
                    v.w = (unsigned)p[6 * NPIX] | ((unsigned)p[7 * NPIX] << 16);
                }
                lds[idx] = v;
            }
            __syncthreads();
            float a[8];
            #pragma unroll
            for (int j = 0; j < 8; ++j) a[j] = 0.f;
            #pragma unroll
            for (int i = 0; i < KSZ; ++i)
                #pragma unroll
                for (int j = 0; j < KSZ; ++j) {
                    const f16x8 v8 = *(const f16x8*)&lds[lb + i * DIL * C + j * DIL];
                    const float e = score[i * KSZ + j];
                    #pragma unroll
                    for (int d = 0; d < 8; ++d)
                        a[d] += e * (float)v8[d];      // v_fma_mix_f32
                }
            #pragma unroll
            for (int t = 0; t < 4; ++t) {
                const __bf16 b0 = (__bf16)(a[2 * t] * inv);
                const __bf16 b1 = (__bf16)(a[2 * t + 1] * inv);
                out_lds[rr * 4 + t][threadIdx.x] =
                    (unsigned)bfbits(b0) | ((unsigned)bfbits(b1) << 16);
            }
        }
        // cooperative half-record write: 2 lanes cover one 32B half-segment
        __syncthreads();
        #pragma unroll
        for (int it = 0; it < 2; ++it) {
            const int linear = it * 256 + threadIdx.x;
            const int px = linear >> 1;        // tile-local pixel 0..255
            const int c  = linear & 1;         // 16B part within the 32B half
            const int gpix = (h0 + (px >> 5)) * WDIM + w0 + (px & 31);
            uint4 val = make_uint4(out_lds[c * 4 + 0][px], out_lds[c * 4 + 1][px],
                                   out_lds[c * 4 + 2][px], out_lds[c * 4 + 3][px]);
            *((uint4*)((unsigned*)(oh + (size_t)gpix * 192) + half * 8) + c) = val;
        }
        // next half's staging barrier orders these reads before refill
    }
}

// Flattened 864-block grid, XCD-chunked: XCD x gets wgs [x*108,(x+1)*108) =
// 3 complete (b,head) panels (one big k=9, one mid k=7, one small), so halo
// re-reads hit the XCD's private L2 and per-XCD work is balanced.
__global__ __launch_bounds__(256) void attn_kernel(
    const unsigned short* __restrict__ qkv, Bias6 bs, __bf16* __restrict__ ATh)
{
    __shared__ uint4 lds[MAX_REGION];
    __shared__ unsigned out_lds[8][256];

    const int orig = blockIdx.x;
    const int wg = (orig & 7) * 108 + (orig >> 3);
    const int panel = wg / 36;
    const int tile = wg - panel * 36;
    const int chunk = panel / 3, slot = panel - chunk * 3;
    int head, b;
    if (slot == 0)      { head = 4 + (chunk >> 2); b = chunk & 3; }
    else if (slot == 1) { head = 2 + (chunk >> 2); b = chunk & 3; }
    else                { head = (chunk < 4) ? 1 : 0; b = chunk & 3; }
    const int tx = tile % 3, ty = tile / 3;
    const int w0 = tx * 32, h0 = ty * 8;

    const unsigned short* Qs = qkv + ((size_t)b * 576 + head * 32) * NPIX;
    const unsigned short* Ks = Qs + (size_t)192 * NPIX;
    const unsigned short* Vs = Qs + (size_t)384 * NPIX;
    __bf16* oh = ATh + (size_t)b * NPIX * 192 + head * 32;
    const float* bias = bs.p[head];

    switch (head) {
        case 0: attn_body<3, 1>(Qs, Ks, Vs, bias, oh, h0, w0, lds, out_lds); break;
        case 1: attn_body<5, 2>(Qs, Ks, Vs, bias, oh, h0, w0, lds, out_lds); break;
        case 2: attn_body<7, 1>(Qs, Ks, Vs, bias, oh, h0, w0, lds, out_lds); break;
        case 3: attn_body<7, 3>(Qs, Ks, Vs, bias, oh, h0, w0, lds, out_lds); break;
        case 4: attn_body<9, 1>(Qs, Ks, Vs, bias, oh, h0, w0, lds, out_lds); break;
        case 5: attn_body<9, 2>(Qs, Ks, Vs, bias, oh, h0, w0, lds, out_lds); break;
    }
}

// ---------------------------------------------------------------------------
extern "C" void kernel_launch(void* const* d_in, const int* in_sizes, int n_in,
                              void* d_out, int out_size, void* d_ws, size_t ws_size,
                              hipStream_t stream) {
    const float* x     = (const float*)d_in[0];   // [4][192][96][96]
    const float* w_qkv = (const float*)d_in[1];   // [576][192]
    const float* w_out = (const float*)d_in[2];   // [192][192]
    Bias6 bs;
    for (int i = 0; i < 6; ++i) bs.p[i] = (const float*)d_in[3 + i];
    float* out = (float*)d_out;                   // [4][192][96][96]

    char* ws = (char*)d_ws;
    _Float16* QKV = (_Float16*)ws;      ws += (size_t)BATCH * 576 * NPIX * 2;   // 42.5 MB
    __bf16* Xh  = (__bf16*)ws;          ws += (size_t)BATCH * NPIX * 192 * 2;   // 14.2 MB
    __bf16* ATh = (__bf16*)ws;          ws += (size_t)BATCH * NPIX * 192 * 2;   // 14.2 MB
    __bf16* W1h = (__bf16*)ws;          ws += (size_t)576 * 192 * 2;
    __bf16* W1l = (__bf16*)ws;          ws += (size_t)576 * 192 * 2;
    __bf16* W2h = (__bf16*)ws;          ws += (size_t)192 * 192 * 2;
    __bf16* W2l = (__bf16*)ws;          ws += (size_t)192 * 192 * 2;

    // 1) weight + input conversion to bf16
    convert_w<<<dim3((576 * 192 + 255) / 256), 256, 0, stream>>>(
        w_qkv, W1h, W1l, 576 * 192, w_out, W2h, W2l, 192 * 192);
    convert_x<<<dim3(NPIX / 64, 192 / 32, BATCH), 256, 0, stream>>>(x, Xh);

    // 2) qkv projection (MFMA): f16 planes [B][576][NPIX]
    gemm_mfma<_Float16><<<dim3(NPIX / 128, 576 / 64, BATCH), 256, 0, stream>>>(
        W1h, W1l, Xh, QKV, 576);

    // 3) neighborhood attention -> bf16 records (coalesced)
    attn_kernel<<<dim3(864), 256, 0, stream>>>((const unsigned short*)QKV, bs, ATh);

    // 4) out projection (MFMA) -> d_out fp32 planes
    gemm_mfma<float><<<dim3(NPIX / 128, 192 / 64, BATCH), 256, 0, stream>>>(
        W2h, W2l, ATh, out, 192);
}

// Round 10
// 98.983 us; speedup vs baseline: 3.3289x; 3.3289x over previous
//
#include <hip/hip_runtime.h>
#include <hip/hip_bf16.h>
#include <math.h>

// Problem constants
#define NPIX 9216   // 96*96
#define HDIM 96
#define WDIM 96
#define NHEADS 6
#define BATCH 4

typedef __bf16 bf16x8 __attribute__((ext_vector_type(8)));
typedef float  f32x4  __attribute__((ext_vector_type(4)));

struct Bias6 { const float* p[6]; };

// async global->LDS 16B copy (dest must be wave-uniform-base + lane*16)
__device__ __forceinline__ void cp16(void* ldst, const void* gsrc) {
    __builtin_amdgcn_global_load_lds(
        (const __attribute__((address_space(1))) unsigned int*)gsrc,
        (__attribute__((address_space(3))) unsigned int*)ldst, 16, 0, 0);
}

__device__ __forceinline__ unsigned short bfbits(__bf16 x) { return *(unsigned short*)&x; }

__device__ __forceinline__ unsigned packf16(float a, float b) {
    _Float16 ha = (_Float16)a, hb = (_Float16)b;
    return (unsigned)*(unsigned short*)&ha | ((unsigned)*(unsigned short*)&hb << 16);
}

// v_fma_mix_f32: acc += f16half(src0) * {f16half|f32}(src1), f32 accumulate.
// op_sel_hi[i]=1 -> src i is f16 (op_sel[i] picks lo/hi); =0 -> f32.
#define MIX_LL(acc, kk, qq) asm("v_fma_mix_f32 %0, %1, %2, %0 op_sel:[0,0,0] op_sel_hi:[1,1,0]" : "+v"(acc) : "v"(kk), "v"(qq))
#define MIX_HH(acc, kk, qq) asm("v_fma_mix_f32 %0, %1, %2, %0 op_sel:[1,1,0] op_sel_hi:[1,1,0]" : "+v"(acc) : "v"(kk), "v"(qq))
#define MIX_LF(acc, vv, ee) asm("v_fma_mix_f32 %0, %1, %2, %0 op_sel:[0,0,0] op_sel_hi:[1,0,0]" : "+v"(acc) : "v"(vv), "v"(ee))
#define MIX_HF(acc, vv, ee) asm("v_fma_mix_f32 %0, %1, %2, %0 op_sel:[1,0,0] op_sel_hi:[1,0,0]" : "+v"(acc) : "v"(vv), "v"(ee))

// ---------------------------------------------------------------------------
// Weight conversion: fp32 -> bf16 hi/lo (both weight matrices in one launch)
// ---------------------------------------------------------------------------
__global__ __launch_bounds__(256) void convert_w(
    const float* __restrict__ w1, __bf16* __restrict__ h1, __bf16* __restrict__ l1, int n1,
    const float* __restrict__ w2, __bf16* __restrict__ h2, __bf16* __restrict__ l2, int n2)
{
    const int i = blockIdx.x * 256 + threadIdx.x;
    if (i < n1) { float f = w1[i]; __bf16 h = (__bf16)f; h1[i] = h; l1[i] = (__bf16)(f - (float)h); }
    if (i < n2) { float f = w2[i]; __bf16 h = (__bf16)f; h2[i] = h; l2[i] = (__bf16)(f - (float)h); }
}

// ---------------------------------------------------------------------------
// x transpose+convert: [B][192][NPIX] fp32 -> records [B][NPIX][192] bf16 (hi)
// ---------------------------------------------------------------------------
__global__ __launch_bounds__(256) void convert_x(
    const float* __restrict__ x, __bf16* __restrict__ Xh)
{
    __shared__ float t[32][65];
    const int b  = blockIdx.z;
    const int c0 = blockIdx.y * 32;
    const int p0 = blockIdx.x * 64;
    const int tid = threadIdx.x;
    const int pl = tid & 63;
    #pragma unroll
    for (int i = 0; i < 8; ++i) {
        const int c = i * 4 + (tid >> 6);
        t[c][pl] = x[((size_t)b * 192 + c0 + c) * NPIX + p0 + pl];
    }
    __syncthreads();
    const int p  = tid >> 2;
    const int cq = (tid & 3) * 8;
    bf16x8 vh;
    #pragma unroll
    for (int j = 0; j < 8; ++j)
        vh[j] = (__bf16)t[cq + j][p];
    *(bf16x8*)(Xh + ((size_t)b * NPIX + p0 + p) * 192 + c0 + cq) = vh;
}

// ---------------------------------------------------------------------------
// bf16 MFMA GEMM (2-product, weights exact): Y[b][m][n] = sum_k W[m][k]*X[b][n][k]
// m97 structure: BM=64 BN=128 BK=64; global_load_lds staging + chunk-XOR swizzle.
// MODE 0: Y float planes [B][M][NPIX] (final output)
// MODE 1: Y f16 channel-pair u32 planes [B][M/2][NPIX]; plane p holds
//         channels (2p, 2p+1) packed (lo,hi).
// ---------------------------------------------------------------------------
template<int MODE>
__global__ __launch_bounds__(256) void gemm_mfma(
    const __bf16* __restrict__ Ah, const __bf16* __restrict__ Al,
    const __bf16* __restrict__ Bh,
    void* __restrict__ Yv, int M)
{
    __shared__ __bf16 sAh[64 * 64];    // [row][64ch], 8 KB, chunk-swizzled
    __shared__ __bf16 sAl[64 * 64];
    __shared__ __bf16 sBh[128 * 64];   // 16 KB

    const int b  = blockIdx.z;
    const int n0 = blockIdx.x * 128;
    const int m0 = blockIdx.y * 64;
    const int tid  = threadIdx.x;
    const int lane = tid & 63;
    const int wid  = tid >> 6;
    const int wr = wid >> 1, wc = wid & 1;
    const int lr = lane & 15;
    const int kg = lane >> 4;

    const char* gA_h = (const char*)Ah + (size_t)m0 * 384;
    const char* gA_l = (const char*)Al + (size_t)m0 * 384;
    const char* gB   = (const char*)Bh + ((size_t)b * NPIX + n0) * 384;

    f32x4 acc[2][4];
    #pragma unroll
    for (int mf = 0; mf < 2; ++mf)
        #pragma unroll
        for (int nf = 0; nf < 4; ++nf)
            acc[mf][nf] = (f32x4){0.f, 0.f, 0.f, 0.f};

    for (int ks = 0; ks < 3; ++ks) {
        if (ks) __syncthreads();
        const int kb = ks * 128;              // byte offset of k-step in a row
        #pragma unroll
        for (int it = 0; it < 2; ++it) {
            const int d  = it * 256 + tid;    // 0..511
            const int rd = d >> 3, cd = d & 7;
            const size_t src = (size_t)rd * 384 + kb + ((cd ^ (rd & 7)) << 4);
            cp16((char*)sAh + d * 16, gA_h + src);
            cp16((char*)sAl + d * 16, gA_l + src);
        }
        #pragma unroll
        for (int it = 0; it < 4; ++it) {
            const int d  = it * 256 + tid;    // 0..1023
            const int rd = d >> 3, cd = d & 7;
            const size_t src = (size_t)rd * 384 + kb + ((cd ^ (rd & 7)) << 4);
            cp16((char*)sBh + d * 16, gB + src);
        }
        __syncthreads();    // drains vmcnt for the async LDS writes
        #pragma unroll
        for (int s = 0; s < 2; ++s) {
            bf16x8 aH[2], aL[2], bH[4];
            #pragma unroll
            for (int mf = 0; mf < 2; ++mf) {
                const int row = wr * 32 + mf * 16 + lr;
                const int c = (s * 4 + kg) ^ (row & 7);
                aH[mf] = *(const bf16x8*)((const char*)sAh + row * 128 + c * 16);
                aL[mf] = *(const bf16x8*)((const char*)sAl + row * 128 + c * 16);
            }
            #pragma unroll
            for (int nf = 0; nf < 4; ++nf) {
                const int row = wc * 64 + nf * 16 + lr;
                const int c = (s * 4 + kg) ^ (row & 7);
                bH[nf] = *(const bf16x8*)((const char*)sBh + row * 128 + c * 16);
            }
            #pragma unroll
            for (int mf = 0; mf < 2; ++mf)
                #pragma unroll
                for (int nf = 0; nf < 4; ++nf) {
                    acc[mf][nf] = __builtin_amdgcn_mfma_f32_16x16x32_bf16(aH[mf], bH[nf], acc[mf][nf], 0, 0, 0);
                    acc[mf][nf] = __builtin_amdgcn_mfma_f32_16x16x32_bf16(aL[mf], bH[nf], acc[mf][nf], 0, 0, 0);
                }
        }
    }

    // D layout: col = lane&15, row = (lane>>4)*4 + r
    if (MODE == 0) {
        float* Yb = (float*)Yv + ((size_t)b * M + m0 + wr * 32) * NPIX + n0 + wc * 64;
        #pragma unroll
        for (int mf = 0; mf < 2; ++mf)
            #pragma unroll
            for (int r = 0; r < 4; ++r) {
                const int row = mf * 16 + kg * 4 + r;
                #pragma unroll
                for (int nf = 0; nf < 4; ++nf)
                    Yb[(size_t)row * NPIX + nf * 16 + lr] = acc[mf][nf][r];
            }
    } else {
        // rows kg*4..kg*4+3 are 4 consecutive channels = 2 complete pairs
        #pragma unroll
        for (int mf = 0; mf < 2; ++mf) {
            const int mbase = m0 + wr * 32 + mf * 16 + kg * 4;   // multiple of 4
            unsigned* Yb = (unsigned*)Yv + ((size_t)b * (M >> 1) + (mbase >> 1)) * NPIX
                         + n0 + wc * 64 + lr;
            #pragma unroll
            for (int nf = 0; nf < 4; ++nf) {
                Yb[nf * 16]        = packf16(acc[mf][nf][0], acc[mf][nf][1]);
                Yb[(size_t)NPIX + nf * 16] = packf16(acc[mf][nf][2], acc[mf][nf][3]);
            }
        }
    }
}

// ---------------------------------------------------------------------------
// LDS-tiled neighborhood attention, f16 channel-pair planes, 8ch per round.
// Inner loops: explicit v_fma_mix_f32 (1 ds_read_b128 + 8 fma per neighbor).
// qkv u32 pair-planes [B][288][NPIX]; output bf16 records [B][NPIX][192].
// ---------------------------------------------------------------------------
#define MAX_REGION 1300   // head (7,3): (8+18) x (32+18)

template<int KSZ, int DIL>
__device__ __forceinline__ void attn_body(
    const unsigned* __restrict__ Qpp, const unsigned* __restrict__ Kpp,
    const unsigned* __restrict__ Vpp, const float* __restrict__ bias,
    __bf16* __restrict__ oh, int h0, int w0,
    uint4* __restrict__ lds,
    unsigned (* __restrict__ out_lds)[256])
{
    constexpr int CC  = KSZ / 2;
    constexpr int HAL = CC * DIL;
    constexpr int R   = 8 + 2 * HAL;
    constexpr int C   = 32 + 2 * HAL;
    constexpr int RC  = R * C;
    constexpr int NN  = KSZ * KSZ;
    const float scale = 0.17677669529663689f;   // 1/sqrt(32)

    const int tx = threadIdx.x & 31;
    const int ty = threadIdx.x >> 5;
    const int pix = (h0 + ty) * WDIM + (w0 + tx);
    const int lb = ty * C + tx;

    float score[NN];
    #pragma unroll
    for (int n = 0; n < NN; ++n) score[n] = 0.f;

    // ---- phase 1: scores (4 rounds of 4 pair-planes = 8 channels) ----
    for (int pp = 0; pp < 16; pp += 4) {
        __syncthreads();
        for (int idx = threadIdx.x; idx < RC; idx += 256) {
            const int r = idx / C, c = idx - r * C;
            const int gh = h0 - HAL + r, gw = w0 - HAL + c;
            uint4 v = make_uint4(0u, 0u, 0u, 0u);
            if ((unsigned)gh < (unsigned)HDIM && (unsigned)gw < (unsigned)WDIM) {
                const unsigned* p = Kpp + (size_t)pp * NPIX + gh * WDIM + gw;
                v.x = p[0 * NPIX];
                v.y = p[1 * NPIX];
                v.z = p[2 * NPIX];
                v.w = p[3 * NPIX];
            }
            lds[idx] = v;
        }
        __syncthreads();
        unsigned qp0 = Qpp[(size_t)(pp + 0) * NPIX + pix];
        unsigned qp1 = Qpp[(size_t)(pp + 1) * NPIX + pix];
        unsigned qp2 = Qpp[(size_t)(pp + 2) * NPIX + pix];
        unsigned qp3 = Qpp[(size_t)(pp + 3) * NPIX + pix];
        #pragma unroll
        for (int i = 0; i < KSZ; ++i)
            #pragma unroll
            for (int j = 0; j < KSZ; ++j) {
                const uint4 k8 = lds[lb + i * DIL * C + j * DIL];
                float s = score[i * KSZ + j];
                MIX_LL(s, k8.x, qp0); MIX_HH(s, k8.x, qp0);
                MIX_LL(s, k8.y, qp1); MIX_HH(s, k8.y, qp1);
                MIX_LL(s, k8.z, qp2); MIX_HH(s, k8.z, qp2);
                MIX_LL(s, k8.w, qp3); MIX_HH(s, k8.w, qp3);
                score[i * KSZ + j] = s;
            }
    }

    // ---- softmax (no max-shift: |scores| < 1 for this distribution) ----
    float l = 0.f;
    #pragma unroll
    for (int n = 0; n < NN; ++n) {
        const float e = __expf(score[n] * scale + bias[n]);
        l += e;
        score[n] = e;
    }
    const float inv = 1.f / l;

    // ---- phase 2: PV (4 rounds of 4 pair-planes) ----
    for (int pp = 0; pp < 16; pp += 4) {
        __syncthreads();
        for (int idx = threadIdx.x; idx < RC; idx += 256) {
            const int r = idx / C, c = idx - r * C;
            const int gh = h0 - HAL + r, gw = w0 - HAL + c;
            uint4 v = make_uint4(0u, 0u, 0u, 0u);
            if ((unsigned)gh < (unsigned)HDIM && (unsigned)gw < (unsigned)WDIM) {
                const unsigned* p = Vpp + (size_t)pp * NPIX + gh * WDIM + gw;
                v.x = p[0 * NPIX];
                v.y = p[1 * NPIX];
                v.z = p[2 * NPIX];
                v.w = p[3 * NPIX];
            }
            lds[idx] = v;
        }
        __syncthreads();
        float a0 = 0.f, a1 = 0.f, a2 = 0.f, a3 = 0.f;
        float a4 = 0.f, a5 = 0.f, a6 = 0.f, a7 = 0.f;
        #pragma unroll
        for (int i = 0; i < KSZ; ++i)
            #pragma unroll
            for (int j = 0; j < KSZ; ++j) {
                const uint4 v8 = lds[lb + i * DIL * C + j * DIL];
                const float e = score[i * KSZ + j];
                MIX_LF(a0, v8.x, e); MIX_HF(a1, v8.x, e);
                MIX_LF(a2, v8.y, e); MIX_HF(a3, v8.y, e);
                MIX_LF(a4, v8.z, e); MIX_HF(a5, v8.z, e);
                MIX_LF(a6, v8.w, e); MIX_HF(a7, v8.w, e);
            }
        const __bf16 c0 = (__bf16)(a0 * inv), c1 = (__bf16)(a1 * inv);
        const __bf16 c2 = (__bf16)(a2 * inv), c3 = (__bf16)(a3 * inv);
        const __bf16 c4 = (__bf16)(a4 * inv), c5 = (__bf16)(a5 * inv);
        const __bf16 c6 = (__bf16)(a6 * inv), c7 = (__bf16)(a7 * inv);
        out_lds[pp + 0][threadIdx.x] = (unsigned)bfbits(c0) | ((unsigned)bfbits(c1) << 16);
        out_lds[pp + 1][threadIdx.x] = (unsigned)bfbits(c2) | ((unsigned)bfbits(c3) << 16);
        out_lds[pp + 2][threadIdx.x] = (unsigned)bfbits(c4) | ((unsigned)bfbits(c5) << 16);
        out_lds[pp + 3][threadIdx.x] = (unsigned)bfbits(c6) | ((unsigned)bfbits(c7) << 16);
    }

    // ---- cooperative coalesced record write: 4 lanes cover one 64B segment ----
    __syncthreads();
    #pragma unroll
    for (int it = 0; it < 4; ++it) {
        const int linear = it * 256 + threadIdx.x;
        const int px = linear >> 2;        // tile-local pixel 0..255
        const int c  = linear & 3;         // 16B part within the 64B segment
        const int gpix = (h0 + (px >> 5)) * WDIM + w0 + (px & 31);
        uint4 val = make_uint4(out_lds[c * 4 + 0][px], out_lds[c * 4 + 1][px],
                               out_lds[c * 4 + 2][px], out_lds[c * 4 + 3][px]);
        *(uint4*)((unsigned*)(oh + (size_t)gpix * 192) + c * 4) = val;
    }
}

// Flattened 864-block grid, XCD-chunked: XCD x gets wgs [x*108,(x+1)*108) =
// 3 complete (b,head) panels (one big k=9, one mid k=7, one small), so halo
// re-reads hit the XCD's private L2 and per-XCD work is balanced.
__global__ __launch_bounds__(256) void attn_kernel(
    const unsigned* __restrict__ qkv, Bias6 bs, __bf16* __restrict__ ATh)
{
    __shared__ uint4 lds[MAX_REGION];
    __shared__ unsigned out_lds[16][256];

    const int orig = blockIdx.x;
    const int wg = (orig & 7) * 108 + (orig >> 3);
    const int panel = wg / 36;
    const int tile = wg - panel * 36;
    const int chunk = panel / 3, slot = panel - chunk * 3;
    int head, b;
    if (slot == 0)      { head = 4 + (chunk >> 2); b = chunk & 3; }
    else if (slot == 1) { head = 2 + (chunk >> 2); b = chunk & 3; }
    else                { head = (chunk < 4) ? 1 : 0; b = chunk & 3; }
    const int tx = tile % 3, ty = tile / 3;
    const int w0 = tx * 32, h0 = ty * 8;

    const unsigned* Qpp = qkv + ((size_t)b * 288 + head * 16) * NPIX;
    const unsigned* Kpp = Qpp + (size_t)96 * NPIX;
    const unsigned* Vpp = Qpp + (size_t)192 * NPIX;
    __bf16* oh = ATh + (size_t)b * NPIX * 192 + head * 32;
    const float* bias = bs.p[head];

    switch (head) {
        case 0: attn_body<3, 1>(Qpp, Kpp, Vpp, bias, oh, h0, w0, lds, out_lds); break;
        case 1: attn_body<5, 2>(Qpp, Kpp, Vpp, bias, oh, h0, w0, lds, out_lds); break;
        case 2: attn_body<7, 1>(Qpp, Kpp, Vpp, bias, oh, h0, w0, lds, out_lds); break;
        case 3: attn_body<7, 3>(Qpp, Kpp, Vpp, bias, oh, h0, w0, lds, out_lds); break;
        case 4: attn_body<9, 1>(Qpp, Kpp, Vpp, bias, oh, h0, w0, lds, out_lds); break;
        case 5: attn_body<9, 2>(Qpp, Kpp, Vpp, bias, oh, h0, w0, lds, out_lds); break;
    }
}

// ---------------------------------------------------------------------------
extern "C" void kernel_launch(void* const* d_in, const int* in_sizes, int n_in,
                              void* d_out, int out_size, void* d_ws, size_t ws_size,
                              hipStream_t stream) {
    const float* x     = (const float*)d_in[0];   // [4][192][96][96]
    const float* w_qkv = (const float*)d_in[1];   // [576][192]
    const float* w_out = (const float*)d_in[2];   // [192][192]
    Bias6 bs;
    for (int i = 0; i < 6; ++i) bs.p[i] = (const float*)d_in[3 + i];
    float* out = (float*)d_out;                   // [4][192][96][96]

    char* ws = (char*)d_ws;
    unsigned* QKV = (unsigned*)ws;      ws += (size_t)BATCH * 288 * NPIX * 4;   // 42.5 MB
    __bf16* Xh  = (__bf16*)ws;          ws += (size_t)BATCH * NPIX * 192 * 2;   // 14.2 MB
    __bf16* ATh = (__bf16*)ws;          ws += (size_t)BATCH * NPIX * 192 * 2;   // 14.2 MB
    __bf16* W1h = (__bf16*)ws;          ws += (size_t)576 * 192 * 2;
    __bf16* W1l = (__bf16*)ws;          ws += (size_t)576 * 192 * 2;
    __bf16* W2h = (__bf16*)ws;          ws += (size_t)192 * 192 * 2;
    __bf16* W2l = (__bf16*)ws;          ws += (size_t)192 * 192 * 2;

    // 1) weight + input conversion to bf16
    convert_w<<<dim3((576 * 192 + 255) / 256), 256, 0, stream>>>(
        w_qkv, W1h, W1l, 576 * 192, w_out, W2h, W2l, 192 * 192);
    convert_x<<<dim3(NPIX / 64, 192 / 32, BATCH), 256, 0, stream>>>(x, Xh);

    // 2) qkv projection (MFMA): f16 pair-planes [B][288][NPIX]
    gemm_mfma<1><<<dim3(NPIX / 128, 576 / 64, BATCH), 256, 0, stream>>>(
        W1h, W1l, Xh, (void*)QKV, 576);

    // 3) neighborhood attention -> bf16 records (coalesced)
    attn_kernel<<<dim3(864), 256, 0, stream>>>(QKV, bs, ATh);

    // 4) out projection (MFMA) -> d_out fp32 planes
    gemm_mfma<0><<<dim3(NPIX / 128, 192 / 64, BATCH), 256, 0, stream>>>(
        W2h, W2l, ATh, (void*)out, 192);
}

// Round 11
// 97.384 us; speedup vs baseline: 3.3836x; 1.0164x over previous
//
#include <hip/hip_runtime.h>
#include <hip/hip_bf16.h>
#include <math.h>

// Problem constants
#define NPIX 9216   // 96*96
#define HDIM 96
#define WDIM 96
#define NHEADS 6
#define BATCH 4

typedef __bf16 bf16x8 __attribute__((ext_vector_type(8)));
typedef float  f32x4  __attribute__((ext_vector_type(4)));

struct Bias6 { const float* p[6]; };

// async global->LDS 16B copy (dest must be wave-uniform-base + lane*16)
__device__ __forceinline__ void cp16(void* ldst, const void* gsrc) {
    __builtin_amdgcn_global_load_lds(
        (const __attribute__((address_space(1))) unsigned int*)gsrc,
        (__attribute__((address_space(3))) unsigned int*)ldst, 16, 0, 0);
}

__device__ __forceinline__ unsigned short bfbits(__bf16 x) { return *(unsigned short*)&x; }

__device__ __forceinline__ unsigned packf16(float a, float b) {
    _Float16 ha = (_Float16)a, hb = (_Float16)b;
    return (unsigned)*(unsigned short*)&ha | ((unsigned)*(unsigned short*)&hb << 16);
}

// v_fma_mix_f32: acc += f16half(src0) * {f16half|f32}(src1), f32 accumulate.
#define MIX_LL(acc, kk, qq) asm("v_fma_mix_f32 %0, %1, %2, %0 op_sel:[0,0,0] op_sel_hi:[1,1,0]" : "+v"(acc) : "v"(kk), "v"(qq))
#define MIX_HH(acc, kk, qq) asm("v_fma_mix_f32 %0, %1, %2, %0 op_sel:[1,1,0] op_sel_hi:[1,1,0]" : "+v"(acc) : "v"(kk), "v"(qq))
#define MIX_LF(acc, vv, ee) asm("v_fma_mix_f32 %0, %1, %2, %0 op_sel:[0,0,0] op_sel_hi:[1,0,0]" : "+v"(acc) : "v"(vv), "v"(ee))
#define MIX_HF(acc, vv, ee) asm("v_fma_mix_f32 %0, %1, %2, %0 op_sel:[1,0,0] op_sel_hi:[1,0,0]" : "+v"(acc) : "v"(vv), "v"(ee))

// ---------------------------------------------------------------------------
// Weight conversion: fp32 -> bf16 hi/lo (both weight matrices in one launch)
// ---------------------------------------------------------------------------
__global__ __launch_bounds__(256) void convert_w(
    const float* __restrict__ w1, __bf16* __restrict__ h1, __bf16* __restrict__ l1, int n1,
    const float* __restrict__ w2, __bf16* __restrict__ h2, __bf16* __restrict__ l2, int n2)
{
    const int i = blockIdx.x * 256 + threadIdx.x;
    if (i < n1) { float f = w1[i]; __bf16 h = (__bf16)f; h1[i] = h; l1[i] = (__bf16)(f - (float)h); }
    if (i < n2) { float f = w2[i]; __bf16 h = (__bf16)f; h2[i] = h; l2[i] = (__bf16)(f - (float)h); }
}

// ---------------------------------------------------------------------------
// x transpose+convert: [B][192][NPIX] fp32 -> records [B][NPIX][192] bf16 (hi)
// ---------------------------------------------------------------------------
__global__ __launch_bounds__(256) void convert_x(
    const float* __restrict__ x, __bf16* __restrict__ Xh)
{
    __shared__ float t[32][65];
    const int b  = blockIdx.z;
    const int c0 = blockIdx.y * 32;
    const int p0 = blockIdx.x * 64;
    const int tid = threadIdx.x;
    const int pl = tid & 63;
    #pragma unroll
    for (int i = 0; i < 8; ++i) {
        const int c = i * 4 + (tid >> 6);
        t[c][pl] = x[((size_t)b * 192 + c0 + c) * NPIX + p0 + pl];
    }
    __syncthreads();
    const int p  = tid >> 2;
    const int cq = (tid & 3) * 8;
    bf16x8 vh;
    #pragma unroll
    for (int j = 0; j < 8; ++j)
        vh[j] = (__bf16)t[cq + j][p];
    *(bf16x8*)(Xh + ((size_t)b * NPIX + p0 + p) * 192 + c0 + cq) = vh;
}

// ---------------------------------------------------------------------------
// bf16 MFMA GEMM (2-product, weights exact): Y[b][m][n] = sum_k W[m][k]*X[b][n][k]
// m97 structure: BM=64 BN=128 BK=64; global_load_lds staging + chunk-XOR swizzle.
// MODE 0: Y float planes [B][M][NPIX] (final output)
// MODE 1: Y f16 channel-OCTET planes [B][M/8][NPIX] x uint4: plane o, pixel n
//         holds channels 8o..8o+7 as 4 packed f16-pairs.
// ---------------------------------------------------------------------------
template<int MODE>
__global__ __launch_bounds__(256) void gemm_mfma(
    const __bf16* __restrict__ Ah, const __bf16* __restrict__ Al,
    const __bf16* __restrict__ Bh,
    void* __restrict__ Yv, int M)
{
    __shared__ __bf16 sAh[64 * 64];    // [row][64ch], 8 KB, chunk-swizzled
    __shared__ __bf16 sAl[64 * 64];
    __shared__ __bf16 sBh[128 * 64];   // 16 KB

    const int b  = blockIdx.z;
    const int n0 = blockIdx.x * 128;
    const int m0 = blockIdx.y * 64;
    const int tid  = threadIdx.x;
    const int lane = tid & 63;
    const int wid  = tid >> 6;
    const int wr = wid >> 1, wc = wid & 1;
    const int lr = lane & 15;
    const int kg = lane >> 4;

    const char* gA_h = (const char*)Ah + (size_t)m0 * 384;
    const char* gA_l = (const char*)Al + (size_t)m0 * 384;
    const char* gB   = (const char*)Bh + ((size_t)b * NPIX + n0) * 384;

    f32x4 acc[2][4];
    #pragma unroll
    for (int mf = 0; mf < 2; ++mf)
        #pragma unroll
        for (int nf = 0; nf < 4; ++nf)
            acc[mf][nf] = (f32x4){0.f, 0.f, 0.f, 0.f};

    for (int ks = 0; ks < 3; ++ks) {
        if (ks) __syncthreads();
        const int kb = ks * 128;              // byte offset of k-step in a row
        #pragma unroll
        for (int it = 0; it < 2; ++it) {
            const int d  = it * 256 + tid;    // 0..511
            const int rd = d >> 3, cd = d & 7;
            const size_t src = (size_t)rd * 384 + kb + ((cd ^ (rd & 7)) << 4);
            cp16((char*)sAh + d * 16, gA_h + src);
            cp16((char*)sAl + d * 16, gA_l + src);
        }
        #pragma unroll
        for (int it = 0; it < 4; ++it) {
            const int d  = it * 256 + tid;    // 0..1023
            const int rd = d >> 3, cd = d & 7;
            const size_t src = (size_t)rd * 384 + kb + ((cd ^ (rd & 7)) << 4);
            cp16((char*)sBh + d * 16, gB + src);
        }
        __syncthreads();    // drains vmcnt for the async LDS writes
        #pragma unroll
        for (int s = 0; s < 2; ++s) {
            bf16x8 aH[2], aL[2], bH[4];
            #pragma unroll
            for (int mf = 0; mf < 2; ++mf) {
                const int row = wr * 32 + mf * 16 + lr;
                const int c = (s * 4 + kg) ^ (row & 7);
                aH[mf] = *(const bf16x8*)((const char*)sAh + row * 128 + c * 16);
                aL[mf] = *(const bf16x8*)((const char*)sAl + row * 128 + c * 16);
            }
            #pragma unroll
            for (int nf = 0; nf < 4; ++nf) {
                const int row = wc * 64 + nf * 16 + lr;
                const int c = (s * 4 + kg) ^ (row & 7);
                bH[nf] = *(const bf16x8*)((const char*)sBh + row * 128 + c * 16);
            }
            #pragma unroll
            for (int mf = 0; mf < 2; ++mf)
                #pragma unroll
                for (int nf = 0; nf < 4; ++nf) {
                    acc[mf][nf] = __builtin_amdgcn_mfma_f32_16x16x32_bf16(aH[mf], bH[nf], acc[mf][nf], 0, 0, 0);
                    acc[mf][nf] = __builtin_amdgcn_mfma_f32_16x16x32_bf16(aL[mf], bH[nf], acc[mf][nf], 0, 0, 0);
                }
        }
    }

    // D layout: col = lane&15, row = (lane>>4)*4 + r
    if (MODE == 0) {
        float* Yb = (float*)Yv + ((size_t)b * M + m0 + wr * 32) * NPIX + n0 + wc * 64;
        #pragma unroll
        for (int mf = 0; mf < 2; ++mf)
            #pragma unroll
            for (int r = 0; r < 4; ++r) {
                const int row = mf * 16 + kg * 4 + r;
                #pragma unroll
                for (int nf = 0; nf < 4; ++nf)
                    Yb[(size_t)row * NPIX + nf * 16 + lr] = acc[mf][nf][r];
            }
    } else {
        // rows kg*4..kg*4+3 = channels cbase..cbase+3 = pairs (kg&1)*2,+1 of
        // octet cbase>>3
        #pragma unroll
        for (int mf = 0; mf < 2; ++mf) {
            const int cbase = m0 + wr * 32 + mf * 16 + kg * 4;
            unsigned* Yq = (unsigned*)Yv
                + (((size_t)b * 72 + (cbase >> 3)) * NPIX + n0 + wc * 64 + lr) * 4
                + ((kg & 1) << 1);
            #pragma unroll
            for (int nf = 0; nf < 4; ++nf) {
                Yq[(nf * 16) * 4 + 0] = packf16(acc[mf][nf][0], acc[mf][nf][1]);
                Yq[(nf * 16) * 4 + 1] = packf16(acc[mf][nf][2], acc[mf][nf][3]);
            }
        }
    }
}

// ---------------------------------------------------------------------------
// LDS-tiled neighborhood attention, f16 channel-octet planes, 8ch per round.
// Staging: ONE coalesced uint4 load per LDS halo entry. Inner loops: explicit
// v_fma_mix_f32 (1 ds_read_b128 + 8 fma per neighbor-round).
// qkv uint4 octet-planes [B][72][NPIX]; output bf16 records [B][NPIX][192].
// ---------------------------------------------------------------------------
#define MAX_REGION 1300   // head (7,3): (8+18) x (32+18)

template<int KSZ, int DIL>
__device__ __forceinline__ void attn_body(
    const uint4* __restrict__ Qq, const uint4* __restrict__ Kq,
    const uint4* __restrict__ Vq, const float* __restrict__ bias,
    __bf16* __restrict__ oh, int h0, int w0,
    uint4* __restrict__ lds,
    unsigned (* __restrict__ out_lds)[256])
{
    constexpr int CC  = KSZ / 2;
    constexpr int HAL = CC * DIL;
    constexpr int R   = 8 + 2 * HAL;
    constexpr int C   = 32 + 2 * HAL;
    constexpr int RC  = R * C;
    constexpr int NN  = KSZ * KSZ;
    const float scale = 0.17677669529663689f;   // 1/sqrt(32)

    const int tx = threadIdx.x & 31;
    const int ty = threadIdx.x >> 5;
    const int pix = (h0 + ty) * WDIM + (w0 + tx);
    const int lb = ty * C + tx;

    float score[NN];
    #pragma unroll
    for (int n = 0; n < NN; ++n) score[n] = 0.f;

    // ---- phase 1: scores (4 rounds of 1 octet-plane = 8 channels) ----
    for (int pp = 0; pp < 4; ++pp) {
        __syncthreads();
        for (int idx = threadIdx.x; idx < RC; idx += 256) {
            const int r = idx / C, c = idx - r * C;
            const int gh = h0 - HAL + r, gw = w0 - HAL + c;
            uint4 v = make_uint4(0u, 0u, 0u, 0u);
            if ((unsigned)gh < (unsigned)HDIM && (unsigned)gw < (unsigned)WDIM)
                v = Kq[(size_t)pp * NPIX + gh * WDIM + gw];
            lds[idx] = v;
        }
        __syncthreads();
        const uint4 qv = Qq[(size_t)pp * NPIX + pix];
        #pragma unroll
        for (int i = 0; i < KSZ; ++i)
            #pragma unroll
            for (int j = 0; j < KSZ; ++j) {
                const uint4 k8 = lds[lb + i * DIL * C + j * DIL];
                float s = score[i * KSZ + j];
                MIX_LL(s, k8.x, qv.x); MIX_HH(s, k8.x, qv.x);
                MIX_LL(s, k8.y, qv.y); MIX_HH(s, k8.y, qv.y);
                MIX_LL(s, k8.z, qv.z); MIX_HH(s, k8.z, qv.z);
                MIX_LL(s, k8.w, qv.w); MIX_HH(s, k8.w, qv.w);
                score[i * KSZ + j] = s;
            }
    }

    // ---- softmax (no max-shift: |scores| < 1 for this distribution) ----
    float l = 0.f;
    #pragma unroll
    for (int n = 0; n < NN; ++n) {
        const float e = __expf(score[n] * scale + bias[n]);
        l += e;
        score[n] = e;
    }
    const float inv = 1.f / l;

    // ---- phase 2: PV, two half-records of 16 channels (8KB out tile) ----
    #pragma unroll
    for (int half = 0; half < 2; ++half) {
        #pragma unroll
        for (int rr = 0; rr < 2; ++rr) {
            const int pp = half * 2 + rr;
            __syncthreads();
            for (int idx = threadIdx.x; idx < RC; idx += 256) {
                const int r = idx / C, c = idx - r * C;
                const int gh = h0 - HAL + r, gw = w0 - HAL + c;
                uint4 v = make_uint4(0u, 0u, 0u, 0u);
                if ((unsigned)gh < (unsigned)HDIM && (unsigned)gw < (unsigned)WDIM)
                    v = Vq[(size_t)pp * NPIX + gh * WDIM + gw];
                lds[idx] = v;
            }
            __syncthreads();
            float a0 = 0.f, a1 = 0.f, a2 = 0.f, a3 = 0.f;
            float a4 = 0.f, a5 = 0.f, a6 = 0.f, a7 = 0.f;
            #pragma unroll
            for (int i = 0; i < KSZ; ++i)
                #pragma unroll
                for (int j = 0; j < KSZ; ++j) {
                    const uint4 v8 = lds[lb + i * DIL * C + j * DIL];
                    const float e = score[i * KSZ + j];
                    MIX_LF(a0, v8.x, e); MIX_HF(a1, v8.x, e);
                    MIX_LF(a2, v8.y, e); MIX_HF(a3, v8.y, e);
                    MIX_LF(a4, v8.z, e); MIX_HF(a5, v8.z, e);
                    MIX_LF(a6, v8.w, e); MIX_HF(a7, v8.w, e);
                }
            const __bf16 c0 = (__bf16)(a0 * inv), c1 = (__bf16)(a1 * inv);
            const __bf16 c2 = (__bf16)(a2 * inv), c3 = (__bf16)(a3 * inv);
            const __bf16 c4 = (__bf16)(a4 * inv), c5 = (__bf16)(a5 * inv);
            const __bf16 c6 = (__bf16)(a6 * inv), c7 = (__bf16)(a7 * inv);
            out_lds[rr * 4 + 0][threadIdx.x] = (unsigned)bfbits(c0) | ((unsigned)bfbits(c1) << 16);
            out_lds[rr * 4 + 1][threadIdx.x] = (unsigned)bfbits(c2) | ((unsigned)bfbits(c3) << 16);
            out_lds[rr * 4 + 2][threadIdx.x] = (unsigned)bfbits(c4) | ((unsigned)bfbits(c5) << 16);
            out_lds[rr * 4 + 3][threadIdx.x] = (unsigned)bfbits(c6) | ((unsigned)bfbits(c7) << 16);
        }
        // cooperative half-record write: 2 lanes cover one 32B half-segment
        __syncthreads();
        #pragma unroll
        for (int it = 0; it < 2; ++it) {
            const int linear = it * 256 + threadIdx.x;
            const int px = linear >> 1;        // tile-local pixel 0..255
            const int c  = linear & 1;         // 16B part within the 32B half
            const int gpix = (h0 + (px >> 5)) * WDIM + w0 + (px & 31);
            uint4 val = make_uint4(out_lds[c * 4 + 0][px], out_lds[c * 4 + 1][px],
                                   out_lds[c * 4 + 2][px], out_lds[c * 4 + 3][px]);
            *((uint4*)((unsigned*)(oh + (size_t)gpix * 192)) + half * 2 + c) = val;
        }
        // next half's staging barrier orders these out_lds reads before refill
    }
}

// Flattened 864-block grid, XCD-chunked: XCD x gets wgs [x*108,(x+1)*108) =
// 3 complete (b,head) panels (one big k=9, one mid k=7, one small), so halo
// re-reads hit the XCD's private L2 and per-XCD work is balanced.
__global__ __launch_bounds__(256) void attn_kernel(
    const uint4* __restrict__ qkv, Bias6 bs, __bf16* __restrict__ ATh)
{
    __shared__ uint4 lds[MAX_REGION];
    __shared__ unsigned out_lds[8][256];

    const int orig = blockIdx.x;
    const int wg = (orig & 7) * 108 + (orig >> 3);
    const int panel = wg / 36;
    const int tile = wg - panel * 36;
    const int chunk = panel / 3, slot = panel - chunk * 3;
    int head, b;
    if (slot == 0)      { head = 4 + (chunk >> 2); b = chunk & 3; }
    else if (slot == 1) { head = 2 + (chunk >> 2); b = chunk & 3; }
    else                { head = (chunk < 4) ? 1 : 0; b = chunk & 3; }
    const int tx = tile % 3, ty = tile / 3;
    const int w0 = tx * 32, h0 = ty * 8;

    const uint4* base = qkv + (size_t)b * 72 * NPIX;
    const uint4* Qq = base + (size_t)(head * 4) * NPIX;
    const uint4* Kq = base + (size_t)(24 + head * 4) * NPIX;
    const uint4* Vq = base + (size_t)(48 + head * 4) * NPIX;
    __bf16* oh = ATh + (size_t)b * NPIX * 192 + head * 32;
    const float* bias = bs.p[head];

    switch (head) {
        case 0: attn_body<3, 1>(Qq, Kq, Vq, bias, oh, h0, w0, lds, out_lds); break;
        case 1: attn_body<5, 2>(Qq, Kq, Vq, bias, oh, h0, w0, lds, out_lds); break;
        case 2: attn_body<7, 1>(Qq, Kq, Vq, bias, oh, h0, w0, lds, out_lds); break;
        case 3: attn_body<7, 3>(Qq, Kq, Vq, bias, oh, h0, w0, lds, out_lds); break;
        case 4: attn_body<9, 1>(Qq, Kq, Vq, bias, oh, h0, w0, lds, out_lds); break;
        case 5: attn_body<9, 2>(Qq, Kq, Vq, bias, oh, h0, w0, lds, out_lds); break;
    }
}

// ---------------------------------------------------------------------------
extern "C" void kernel_launch(void* const* d_in, const int* in_sizes, int n_in,
                              void* d_out, int out_size, void* d_ws, size_t ws_size,
                              hipStream_t stream) {
    const float* x     = (const float*)d_in[0];   // [4][192][96][96]
    const float* w_qkv = (const float*)d_in[1];   // [576][192]
    const float* w_out = (const float*)d_in[2];   // [192][192]
    Bias6 bs;
    for (int i = 0; i < 6; ++i) bs.p[i] = (const float*)d_in[3 + i];
    float* out = (float*)d_out;                   // [4][192][96][96]

    char* ws = (char*)d_ws;
    uint4* QKV = (uint4*)ws;            ws += (size_t)BATCH * 72 * NPIX * 16;   // 42.5 MB
    __bf16* Xh  = (__bf16*)ws;          ws += (size_t)BATCH * NPIX * 192 * 2;   // 14.2 MB
    __bf16* ATh = (__bf16*)ws;          ws += (size_t)BATCH * NPIX * 192 * 2;   // 14.2 MB
    __bf16* W1h = (__bf16*)ws;          ws += (size_t)576 * 192 * 2;
    __bf16* W1l = (__bf16*)ws;          ws += (size_t)576 * 192 * 2;
    __bf16* W2h = (__bf16*)ws;          ws += (size_t)192 * 192 * 2;
    __bf16* W2l = (__bf16*)ws;          ws += (size_t)192 * 192 * 2;

    // 1) weight + input conversion to bf16
    convert_w<<<dim3((576 * 192 + 255) / 256), 256, 0, stream>>>(
        w_qkv, W1h, W1l, 576 * 192, w_out, W2h, W2l, 192 * 192);
    convert_x<<<dim3(NPIX / 64, 192 / 32, BATCH), 256, 0, stream>>>(x, Xh);

    // 2) qkv projection (MFMA): f16 octet-planes [B][72][NPIX] x uint4
    gemm_mfma<1><<<dim3(NPIX / 128, 576 / 64, BATCH), 256, 0, stream>>>(
        W1h, W1l, Xh, (void*)QKV, 576);

    // 3) neighborhood attention -> bf16 records (coalesced)
    attn_kernel<<<dim3(864), 256, 0, stream>>>(QKV, bs, ATh);

    // 4) out projection (MFMA) -> d_out fp32 planes
    gemm_mfma<0><<<dim3(NPIX / 128, 192 / 64, BATCH), 256, 0, stream>>>(
        W2h, W2l, ATh, (void*)out, 192);
}

// Round 12
// 94.697 us; speedup vs baseline: 3.4796x; 1.0284x over previous
//
#include <hip/hip_runtime.h>
#include <hip/hip_bf16.h>
#include <math.h>

// Problem constants
#define NPIX 9216   // 96*96
#define HDIM 96
#define WDIM 96
#define NHEADS 6
#define BATCH 4

typedef __bf16 bf16x8 __attribute__((ext_vector_type(8)));
typedef float  f32x4  __attribute__((ext_vector_type(4)));

struct Bias6 { const float* p[6]; };

// async global->LDS 16B copy (dest: wave-uniform base + lane*16)
__device__ __forceinline__ void cp16(void* ldst, const void* gsrc) {
    __builtin_amdgcn_global_load_lds(
        (const __attribute__((address_space(1))) unsigned int*)gsrc,
        (__attribute__((address_space(3))) unsigned int*)ldst, 16, 0, 0);
}

__device__ __forceinline__ unsigned short bfbits(__bf16 x) { return *(unsigned short*)&x; }

__device__ __forceinline__ unsigned packf16(float a, float b) {
    _Float16 ha = (_Float16)a, hb = (_Float16)b;
    return (unsigned)*(unsigned short*)&ha | ((unsigned)*(unsigned short*)&hb << 16);
}

template<int N>
__device__ __forceinline__ void waitcnt_vm() {
    if constexpr (N == 0) asm volatile("s_waitcnt vmcnt(0)" ::: "memory");
    else if constexpr (N == 2) asm volatile("s_waitcnt vmcnt(2)" ::: "memory");
    else if constexpr (N == 3) asm volatile("s_waitcnt vmcnt(3)" ::: "memory");
    else if constexpr (N == 5) asm volatile("s_waitcnt vmcnt(5)" ::: "memory");
    else asm volatile("s_waitcnt vmcnt(0)" ::: "memory");
    __builtin_amdgcn_sched_barrier(0);
}

// v_fma_mix_f32: acc += f16half(src0) * {f16half|f32}(src1), f32 accumulate.
#define MIX_LL(acc, kk, qq) asm("v_fma_mix_f32 %0, %1, %2, %0 op_sel:[0,0,0] op_sel_hi:[1,1,0]" : "+v"(acc) : "v"(kk), "v"(qq))
#define MIX_HH(acc, kk, qq) asm("v_fma_mix_f32 %0, %1, %2, %0 op_sel:[1,1,0] op_sel_hi:[1,1,0]" : "+v"(acc) : "v"(kk), "v"(qq))
#define MIX_LF(acc, vv, ee) asm("v_fma_mix_f32 %0, %1, %2, %0 op_sel:[0,0,0] op_sel_hi:[1,0,0]" : "+v"(acc) : "v"(vv), "v"(ee))
#define MIX_HF(acc, vv, ee) asm("v_fma_mix_f32 %0, %1, %2, %0 op_sel:[1,0,0] op_sel_hi:[1,0,0]" : "+v"(acc) : "v"(vv), "v"(ee))

// ---------------------------------------------------------------------------
// Weight conversion: fp32 -> bf16 hi/lo
// ---------------------------------------------------------------------------
__global__ __launch_bounds__(256) void convert_w(
    const float* __restrict__ w1, __bf16* __restrict__ h1, __bf16* __restrict__ l1, int n1,
    const float* __restrict__ w2, __bf16* __restrict__ h2, __bf16* __restrict__ l2, int n2)
{
    const int i = blockIdx.x * 256 + threadIdx.x;
    if (i < n1) { float f = w1[i]; __bf16 h = (__bf16)f; h1[i] = h; l1[i] = (__bf16)(f - (float)h); }
    if (i < n2) { float f = w2[i]; __bf16 h = (__bf16)f; h2[i] = h; l2[i] = (__bf16)(f - (float)h); }
}

// ---------------------------------------------------------------------------
// x transpose+convert: [B][192][NPIX] fp32 -> records [B][NPIX][192] bf16 (hi)
// ---------------------------------------------------------------------------
__global__ __launch_bounds__(256) void convert_x(
    const float* __restrict__ x, __bf16* __restrict__ Xh)
{
    __shared__ float t[32][65];
    const int b  = blockIdx.z;
    const int c0 = blockIdx.y * 32;
    const int p0 = blockIdx.x * 64;
    const int tid = threadIdx.x;
    const int pl = tid & 63;
    #pragma unroll
    for (int i = 0; i < 8; ++i) {
        const int c = i * 4 + (tid >> 6);
        t[c][pl] = x[((size_t)b * 192 + c0 + c) * NPIX + p0 + pl];
    }
    __syncthreads();
    const int p  = tid >> 2;
    const int cq = (tid & 3) * 8;
    bf16x8 vh;
    #pragma unroll
    for (int j = 0; j < 8; ++j)
        vh[j] = (__bf16)t[cq + j][p];
    *(bf16x8*)(Xh + ((size_t)b * NPIX + p0 + p) * 192 + c0 + cq) = vh;
}

// ---------------------------------------------------------------------------
// bf16 MFMA GEMM (2-product, weights exact), m97 structure. (unchanged)
// MODE 0: Y float planes [B][M][NPIX].  MODE 1: f16 octet-planes [B][M/8][NPIX]x uint4.
// ---------------------------------------------------------------------------
template<int MODE>
__global__ __launch_bounds__(256) void gemm_mfma(
    const __bf16* __restrict__ Ah, const __bf16* __restrict__ Al,
    const __bf16* __restrict__ Bh,
    void* __restrict__ Yv, int M)
{
    __shared__ __bf16 sAh[64 * 64];
    __shared__ __bf16 sAl[64 * 64];
    __shared__ __bf16 sBh[128 * 64];

    const int b  = blockIdx.z;
    const int n0 = blockIdx.x * 128;
    const int m0 = blockIdx.y * 64;
    const int tid  = threadIdx.x;
    const int lane = tid & 63;
    const int wid  = tid >> 6;
    const int wr = wid >> 1, wc = wid & 1;
    const int lr = lane & 15;
    const int kg = lane >> 4;

    const char* gA_h = (const char*)Ah + (size_t)m0 * 384;
    const char* gA_l = (const char*)Al + (size_t)m0 * 384;
    const char* gB   = (const char*)Bh + ((size_t)b * NPIX + n0) * 384;

    f32x4 acc[2][4];
    #pragma unroll
    for (int mf = 0; mf < 2; ++mf)
        #pragma unroll
        for (int nf = 0; nf < 4; ++nf)
            acc[mf][nf] = (f32x4){0.f, 0.f, 0.f, 0.f};

    for (int ks = 0; ks < 3; ++ks) {
        if (ks) __syncthreads();
        const int kb = ks * 128;
        #pragma unroll
        for (int it = 0; it < 2; ++it) {
            const int d  = it * 256 + tid;
            const int rd = d >> 3, cd = d & 7;
            const size_t src = (size_t)rd * 384 + kb + ((cd ^ (rd & 7)) << 4);
            cp16((char*)sAh + d * 16, gA_h + src);
            cp16((char*)sAl + d * 16, gA_l + src);
        }
        #pragma unroll
        for (int it = 0; it < 4; ++it) {
            const int d  = it * 256 + tid;
            const int rd = d >> 3, cd = d & 7;
            const size_t src = (size_t)rd * 384 + kb + ((cd ^ (rd & 7)) << 4);
            cp16((char*)sBh + d * 16, gB + src);
        }
        __syncthreads();
        #pragma unroll
        for (int s = 0; s < 2; ++s) {
            bf16x8 aH[2], aL[2], bH[4];
            #pragma unroll
            for (int mf = 0; mf < 2; ++mf) {
                const int row = wr * 32 + mf * 16 + lr;
                const int c = (s * 4 + kg) ^ (row & 7);
                aH[mf] = *(const bf16x8*)((const char*)sAh + row * 128 + c * 16);
                aL[mf] = *(const bf16x8*)((const char*)sAl + row * 128 + c * 16);
            }
            #pragma unroll
            for (int nf = 0; nf < 4; ++nf) {
                const int row = wc * 64 + nf * 16 + lr;
                const int c = (s * 4 + kg) ^ (row & 7);
                bH[nf] = *(const bf16x8*)((const char*)sBh + row * 128 + c * 16);
            }
            #pragma unroll
            for (int mf = 0; mf < 2; ++mf)
                #pragma unroll
                for (int nf = 0; nf < 4; ++nf) {
                    acc[mf][nf] = __builtin_amdgcn_mfma_f32_16x16x32_bf16(aH[mf], bH[nf], acc[mf][nf], 0, 0, 0);
                    acc[mf][nf] = __builtin_amdgcn_mfma_f32_16x16x32_bf16(aL[mf], bH[nf], acc[mf][nf], 0, 0, 0);
                }
        }
    }

    if (MODE == 0) {
        float* Yb = (float*)Yv + ((size_t)b * M + m0 + wr * 32) * NPIX + n0 + wc * 64;
        #pragma unroll
        for (int mf = 0; mf < 2; ++mf)
            #pragma unroll
            for (int r = 0; r < 4; ++r) {
                const int row = mf * 16 + kg * 4 + r;
                #pragma unroll
                for (int nf = 0; nf < 4; ++nf)
                    Yb[(size_t)row * NPIX + nf * 16 + lr] = acc[mf][nf][r];
            }
    } else {
        #pragma unroll
        for (int mf = 0; mf < 2; ++mf) {
            const int cbase = m0 + wr * 32 + mf * 16 + kg * 4;
            unsigned* Yq = (unsigned*)Yv
                + (((size_t)b * 72 + (cbase >> 3)) * NPIX + n0 + wc * 64 + lr) * 4
                + ((kg & 1) << 1);
            #pragma unroll
            for (int nf = 0; nf < 4; ++nf) {
                Yq[(nf * 16) * 4 + 0] = packf16(acc[mf][nf][0], acc[mf][nf][1]);
                Yq[(nf * 16) * 4 + 1] = packf16(acc[mf][nf][2], acc[mf][nf][3]);
            }
        }
    }
}

// ---------------------------------------------------------------------------
// LDS-tiled neighborhood attention, f16 octet planes, pipelined staging.
// DB=true: double-buffered global_load_lds staging, counted vmcnt + raw
// s_barrier (stage r+1 in flight across the barrier while computing r).
// DB=false (head (7,3), region too big for 2 buffers): classic syncthreads.
// 8 rounds: r=0..3 QK octets, r=4..7 PV octets.
// ---------------------------------------------------------------------------
template<int KSZ, int DIL, bool DB, int L>
__device__ __forceinline__ void attn_body(
    const uint4* __restrict__ Qq, const uint4* __restrict__ Kq,
    const uint4* __restrict__ Vq, const float* __restrict__ bias,
    const uint4* __restrict__ guard,
    __bf16* __restrict__ oh, int h0, int w0,
    uint4* __restrict__ bufs,
    unsigned (* __restrict__ out_lds)[256])
{
    constexpr int CC  = KSZ / 2;
    constexpr int HAL = CC * DIL;
    constexpr int R   = 8 + 2 * HAL;
    constexpr int C   = 32 + 2 * HAL;
    constexpr int RC  = R * C;
    constexpr int NN  = KSZ * KSZ;
    const float scale = 0.17677669529663689f;     // 1/sqrt(32)

    const int tid = threadIdx.x;
    const int tx = tid & 31;
    const int ty = tid >> 5;
    const int pix = (h0 + ty) * WDIM + (w0 + tx);
    const int lb = ty * C + tx;

    // preload Q (all 4 octets) so no VMEM loads sit inside the pipelined loop
    uint4 qv[4];
    #pragma unroll
    for (int p = 0; p < 4; ++p) qv[p] = Qq[(size_t)p * NPIX + pix];

    // bias folded into score init: e = exp((dot + bias/scale) * scale)
    float score[NN];
    #pragma unroll
    for (int n = 0; n < NN; ++n) score[n] = bias[n] * 5.656854249492381f;

    // stage round r's octet into its buffer (async, guard page for OOB)
    auto STAGE = [&](int r) {
        const uint4* src = (r < 4) ? (Kq + (size_t)r * NPIX)
                                   : (Vq + (size_t)(r - 4) * NPIX);
        uint4* dst = bufs + (DB ? ((r & 1) * (L * 256)) : 0);
        #pragma unroll
        for (int it = 0; it < L; ++it) {
            const int idx = it * 256 + tid;
            const int rr = idx / C, cc = idx - rr * C;
            const int gh = h0 - HAL + rr, gw = w0 - HAL + cc;
            const bool ok = (idx < RC) && ((unsigned)gh < (unsigned)HDIM)
                                       && ((unsigned)gw < (unsigned)WDIM);
            const uint4* s = ok ? (src + gh * WDIM + gw) : guard;
            cp16(dst + idx, s);
        }
    };

    auto QK = [&](const uint4* buf, int oct) {
        const uint4 q = qv[oct];
        #pragma unroll
        for (int i = 0; i < KSZ; ++i)
            #pragma unroll
            for (int j = 0; j < KSZ; ++j) {
                const uint4 k8 = buf[lb + i * DIL * C + j * DIL];
                float s = score[i * KSZ + j];
                MIX_LL(s, k8.x, q.x); MIX_HH(s, k8.x, q.x);
                MIX_LL(s, k8.y, q.y); MIX_HH(s, k8.y, q.y);
                MIX_LL(s, k8.z, q.z); MIX_HH(s, k8.z, q.z);
                MIX_LL(s, k8.w, q.w); MIX_HH(s, k8.w, q.w);
                score[i * KSZ + j] = s;
            }
    };

    float inv = 0.f;
    auto SOFTMAX = [&]() {
        float l = 0.f;
        #pragma unroll
        for (int n = 0; n < NN; ++n) {
            const float e = __expf(score[n] * scale);
            l += e;
            score[n] = e;
        }
        inv = 1.f / l;
    };

    auto PV = [&](const uint4* buf, int oct) {
        float a0 = 0.f, a1 = 0.f, a2 = 0.f, a3 = 0.f;
        float a4 = 0.f, a5 = 0.f, a6 = 0.f, a7 = 0.f;
        #pragma unroll
        for (int i = 0; i < KSZ; ++i)
            #pragma unroll
            for (int j = 0; j < KSZ; ++j) {
                const uint4 v8 = buf[lb + i * DIL * C + j * DIL];
                const float e = score[i * KSZ + j];
                MIX_LF(a0, v8.x, e); MIX_HF(a1, v8.x, e);
                MIX_LF(a2, v8.y, e); MIX_HF(a3, v8.y, e);
                MIX_LF(a4, v8.z, e); MIX_HF(a5, v8.z, e);
                MIX_LF(a6, v8.w, e); MIX_HF(a7, v8.w, e);
            }
        const int rr = oct & 1;
        const __bf16 c0 = (__bf16)(a0 * inv), c1 = (__bf16)(a1 * inv);
        const __bf16 c2 = (__bf16)(a2 * inv), c3 = (__bf16)(a3 * inv);
        const __bf16 c4 = (__bf16)(a4 * inv), c5 = (__bf16)(a5 * inv);
        const __bf16 c6 = (__bf16)(a6 * inv), c7 = (__bf16)(a7 * inv);
        out_lds[rr * 4 + 0][tid] = (unsigned)bfbits(c0) | ((unsigned)bfbits(c1) << 16);
        out_lds[rr * 4 + 1][tid] = (unsigned)bfbits(c2) | ((unsigned)bfbits(c3) << 16);
        out_lds[rr * 4 + 2][tid] = (unsigned)bfbits(c4) | ((unsigned)bfbits(c5) << 16);
        out_lds[rr * 4 + 3][tid] = (unsigned)bfbits(c6) | ((unsigned)bfbits(c7) << 16);
    };

    auto COOP = [&](int half) {     // coalesced half-record write (16 ch)
        #pragma unroll
        for (int it = 0; it < 2; ++it) {
            const int linear = it * 256 + tid;
            const int px = linear >> 1;
            const int c  = linear & 1;
            const int gpix = (h0 + (px >> 5)) * WDIM + w0 + (px & 31);
            uint4 val = make_uint4(out_lds[c * 4 + 0][px], out_lds[c * 4 + 1][px],
                                   out_lds[c * 4 + 2][px], out_lds[c * 4 + 3][px]);
            *((uint4*)((unsigned*)(oh + (size_t)gpix * 192)) + half * 2 + c) = val;
        }
    };

    if constexpr (DB) {
        STAGE(0);
        #pragma unroll
        for (int r = 0; r < 8; ++r) {
            if (r < 7) STAGE(r + 1);
            if (r < 7) waitcnt_vm<L>(); else waitcnt_vm<0>();  // stage(r) landed
            __builtin_amdgcn_s_barrier();                      // all waves' stage(r) in
            __builtin_amdgcn_sched_barrier(0);
            const uint4* buf = bufs + (r & 1) * (L * 256);
            if (r < 4) {
                QK(buf, r);
                if (r == 3) SOFTMAX();
            } else {
                PV(buf, r - 4);
                asm volatile("s_waitcnt lgkmcnt(0)" ::: "memory");  // publish out_lds
                __builtin_amdgcn_sched_barrier(0);
            }
            __builtin_amdgcn_s_barrier();                      // round done
            __builtin_amdgcn_sched_barrier(0);
            if (r == 5) COOP(0);
            if (r == 7) COOP(1);
        }
    } else {
        #pragma unroll
        for (int r = 0; r < 8; ++r) {
            __syncthreads();                 // prior compute done, buffer free
            if (r == 6) COOP(0);             // reads out_lds before round-6 rewrite
            STAGE(r);
            __syncthreads();                 // implicit vmcnt(0): staged
            const uint4* buf = bufs;
            if (r < 4) {
                QK(buf, r);
                if (r == 3) SOFTMAX();
            } else {
                PV(buf, r - 4);
            }
        }
        __syncthreads();
        COOP(1);
    }
}

// Flattened 864-block grid, XCD-chunked (3 panels per XCD: big/mid/small).
__global__ __launch_bounds__(256) void attn_kernel(
    const uint4* __restrict__ qkv, Bias6 bs, __bf16* __restrict__ ATh,
    const uint4* __restrict__ guard)
{
    __shared__ uint4 bufs[2560];             // 40 KB: 2 x L*256 (L<=5) / h3 single 1536
    __shared__ unsigned out_lds[8][256];     // 8 KB

    const int orig = blockIdx.x;
    const int wg = (orig & 7) * 108 + (orig >> 3);
    const int panel = wg / 36;
    const int tile = wg - panel * 36;
    const int chunk = panel / 3, slot = panel - chunk * 3;
    int head, b;
    if (slot == 0)      { head = 4 + (chunk >> 2); b = chunk & 3; }
    else if (slot == 1) { head = 2 + (chunk >> 2); b = chunk & 3; }
    else                { head = (chunk < 4) ? 1 : 0; b = chunk & 3; }
    const int tx = tile % 3, ty = tile / 3;
    const int w0 = tx * 32, h0 = ty * 8;

    const uint4* base = qkv + (size_t)b * 72 * NPIX;
    const uint4* Qq = base + (size_t)(head * 4) * NPIX;
    const uint4* Kq = base + (size_t)(24 + head * 4) * NPIX;
    const uint4* Vq = base + (size_t)(48 + head * 4) * NPIX;
    __bf16* oh = ATh + (size_t)b * NPIX * 192 + head * 32;
    const float* bias = bs.p[head];

    switch (head) {
        case 0: attn_body<3, 1, true, 2>(Qq, Kq, Vq, bias, guard, oh, h0, w0, bufs, out_lds); break;
        case 1: attn_body<5, 2, true, 3>(Qq, Kq, Vq, bias, guard, oh, h0, w0, bufs, out_lds); break;
        case 2: attn_body<7, 1, true, 3>(Qq, Kq, Vq, bias, guard, oh, h0, w0, bufs, out_lds); break;
        case 3: attn_body<7, 3, false, 6>(Qq, Kq, Vq, bias, guard, oh, h0, w0, bufs, out_lds); break;
        case 4: attn_body<9, 1, true, 3>(Qq, Kq, Vq, bias, guard, oh, h0, w0, bufs, out_lds); break;
        case 5: attn_body<9, 2, true, 5>(Qq, Kq, Vq, bias, guard, oh, h0, w0, bufs, out_lds); break;
    }
}

// ---------------------------------------------------------------------------
extern "C" void kernel_launch(void* const* d_in, const int* in_sizes, int n_in,
                              void* d_out, int out_size, void* d_ws, size_t ws_size,
                              hipStream_t stream) {
    const float* x     = (const float*)d_in[0];   // [4][192][96][96]
    const float* w_qkv = (const float*)d_in[1];   // [576][192]
    const float* w_out = (const float*)d_in[2];   // [192][192]
    Bias6 bs;
    for (int i = 0; i < 6; ++i) bs.p[i] = (const float*)d_in[3 + i];
    float* out = (float*)d_out;                   // [4][192][96][96]

    char* ws = (char*)d_ws;
    uint4* QKV = (uint4*)ws;            ws += (size_t)BATCH * 72 * NPIX * 16;   // 42.5 MB
    __bf16* Xh  = (__bf16*)ws;          ws += (size_t)BATCH * NPIX * 192 * 2;   // 14.2 MB
    __bf16* ATh = (__bf16*)ws;          ws += (size_t)BATCH * NPIX * 192 * 2;   // 14.2 MB
    __bf16* W1h = (__bf16*)ws;          ws += (size_t)576 * 192 * 2;
    __bf16* W1l = (__bf16*)ws;          ws += (size_t)576 * 192 * 2;
    __bf16* W2h = (__bf16*)ws;          ws += (size_t)192 * 192 * 2;
    __bf16* W2l = (__bf16*)ws;          ws += (size_t)192 * 192 * 2;
    uint4* guard = (uint4*)ws;          ws += 1024;                              // zero page

    hipMemsetAsync(guard, 0, 1024, stream);

    // 1) weight + input conversion to bf16
    convert_w<<<dim3((576 * 192 + 255) / 256), 256, 0, stream>>>(
        w_qkv, W1h, W1l, 576 * 192, w_out, W2h, W2l, 192 * 192);
    convert_x<<<dim3(NPIX / 64, 192 / 32, BATCH), 256, 0, stream>>>(x, Xh);

    // 2) qkv projection (MFMA): f16 octet-planes [B][72][NPIX] x uint4
    gemm_mfma<1><<<dim3(NPIX / 128, 576 / 64, BATCH), 256, 0, stream>>>(
        W1h, W1l, Xh, (void*)QKV, 576);

    // 3) neighborhood attention -> bf16 records (coalesced)
    attn_kernel<<<dim3(864), 256, 0, stream>>>(QKV, bs, ATh, guard);

    // 4) out projection (MFMA) -> d_out fp32 planes
    gemm_mfma<0><<<dim3(NPIX / 128, 192 / 64, BATCH), 256, 0, stream>>>(
        W2h, W2l, ATh, (void*)out, 192);
}

// Round 13
// 91.355 us; speedup vs baseline: 3.6069x; 1.0366x over previous
//
#include <hip/hip_runtime.h>
#include <hip/hip_bf16.h>
#include <math.h>

// Problem constants
#define NPIX 9216   // 96*96
#define HDIM 96
#define WDIM 96
#define NHEADS 6
#define BATCH 4

typedef __bf16 bf16x8 __attribute__((ext_vector_type(8)));
typedef float  f32x4  __attribute__((ext_vector_type(4)));

struct Bias6 { const float* p[6]; };

// async global->LDS 16B copy (dest: wave-uniform base + lane*16)
__device__ __forceinline__ void cp16(void* ldst, const void* gsrc) {
    __builtin_amdgcn_global_load_lds(
        (const __attribute__((address_space(1))) unsigned int*)gsrc,
        (__attribute__((address_space(3))) unsigned int*)ldst, 16, 0, 0);
}

__device__ __forceinline__ unsigned short bfbits(__bf16 x) { return *(unsigned short*)&x; }

__device__ __forceinline__ unsigned packf16(float a, float b) {
    _Float16 ha = (_Float16)a, hb = (_Float16)b;
    return (unsigned)*(unsigned short*)&ha | ((unsigned)*(unsigned short*)&hb << 16);
}

template<int N>
__device__ __forceinline__ void waitcnt_vm() {
    if constexpr (N == 0) asm volatile("s_waitcnt vmcnt(0)" ::: "memory");
    else if constexpr (N == 2) asm volatile("s_waitcnt vmcnt(2)" ::: "memory");
    else if constexpr (N == 3) asm volatile("s_waitcnt vmcnt(3)" ::: "memory");
    else if constexpr (N == 5) asm volatile("s_waitcnt vmcnt(5)" ::: "memory");
    else asm volatile("s_waitcnt vmcnt(0)" ::: "memory");
    __builtin_amdgcn_sched_barrier(0);
}

// v_fma_mix_f32: acc += f16half(src0) * {f16half|f32}(src1), f32 accumulate.
#define MIX_LL(acc, kk, qq) asm("v_fma_mix_f32 %0, %1, %2, %0 op_sel:[0,0,0] op_sel_hi:[1,1,0]" : "+v"(acc) : "v"(kk), "v"(qq))
#define MIX_HH(acc, kk, qq) asm("v_fma_mix_f32 %0, %1, %2, %0 op_sel:[1,1,0] op_sel_hi:[1,1,0]" : "+v"(acc) : "v"(kk), "v"(qq))
#define MIX_LF(acc, vv, ee) asm("v_fma_mix_f32 %0, %1, %2, %0 op_sel:[0,0,0] op_sel_hi:[1,0,0]" : "+v"(acc) : "v"(vv), "v"(ee))
#define MIX_HF(acc, vv, ee) asm("v_fma_mix_f32 %0, %1, %2, %0 op_sel:[1,0,0] op_sel_hi:[1,0,0]" : "+v"(acc) : "v"(vv), "v"(ee))

// ---------------------------------------------------------------------------
// x transpose+convert: [B][192][NPIX] fp32 -> records [B][NPIX][192] bf16 (hi)
// The y==0,z==0 block slice additionally converts both weight matrices to
// bf16 hi/lo (147456 elements over 144 blocks x 256 thr x 4 each).
// ---------------------------------------------------------------------------
__global__ __launch_bounds__(256) void convert_x(
    const float* __restrict__ x, __bf16* __restrict__ Xh,
    const float* __restrict__ w1, __bf16* __restrict__ h1, __bf16* __restrict__ l1,
    const float* __restrict__ w2, __bf16* __restrict__ h2, __bf16* __restrict__ l2)
{
    __shared__ float t[32][65];
    const int b  = blockIdx.z;
    const int c0 = blockIdx.y * 32;
    const int p0 = blockIdx.x * 64;
    const int tid = threadIdx.x;

    if (blockIdx.y == 0 && blockIdx.z == 0) {
        const int f = blockIdx.x * 256 + tid;    // 0..36863
        #pragma unroll
        for (int u = 0; u < 4; ++u) {
            const int i = f * 4 + u;             // 0..147455
            if (i < 576 * 192) {
                float v = w1[i]; __bf16 h = (__bf16)v;
                h1[i] = h; l1[i] = (__bf16)(v - (float)h);
            } else {
                const int j = i - 576 * 192;     // 0..36863
                float v = w2[j]; __bf16 h = (__bf16)v;
                h2[j] = h; l2[j] = (__bf16)(v - (float)h);
            }
        }
    }

    const int pl = tid & 63;
    #pragma unroll
    for (int i = 0; i < 8; ++i) {
        const int c = i * 4 + (tid >> 6);
        t[c][pl] = x[((size_t)b * 192 + c0 + c) * NPIX + p0 + pl];
    }
    __syncthreads();
    const int p  = tid >> 2;
    const int cq = (tid & 3) * 8;
    bf16x8 vh;
    #pragma unroll
    for (int j = 0; j < 8; ++j)
        vh[j] = (__bf16)t[cq + j][p];
    *(bf16x8*)(Xh + ((size_t)b * NPIX + p0 + p) * 192 + c0 + cq) = vh;
}

// ---------------------------------------------------------------------------
// bf16 MFMA GEMM, m97 structure. Blocks with m0 >= TWO_FROM (and TWO_FROM
// in range) do the 2-product (Wh+Wl)*Xh; others 1-product Wh*Xh.
// GEMM1 (MODE 1): TWO_FROM=384 -> V rows exact-weight, Q/K rows bf16-weight.
// GEMM2 (MODE 0): TWO_FROM=1024 -> all 1-product.
// MODE 0: Y float planes [B][M][NPIX].  MODE 1: f16 octet-planes [B][M/8][NPIX] x uint4.
// ---------------------------------------------------------------------------
template<int MODE, int TWO_FROM>
__global__ __launch_bounds__(256) void gemm_mfma(
    const __bf16* __restrict__ Ah, const __bf16* __restrict__ Al,
    const __bf16* __restrict__ Bh,
    void* __restrict__ Yv, int M)
{
    __shared__ __bf16 sAh[64 * 64];
    __shared__ __bf16 sAl[64 * 64];
    __shared__ __bf16 sBh[128 * 64];

    const int b  = blockIdx.z;
    const int n0 = blockIdx.x * 128;
    const int m0 = blockIdx.y * 64;
    const bool two = (TWO_FROM < 1024) && (m0 >= TWO_FROM);   // block-uniform
    const int tid  = threadIdx.x;
    const int lane = tid & 63;
    const int wid  = tid >> 6;
    const int wr = wid >> 1, wc = wid & 1;
    const int lr = lane & 15;
    const int kg = lane >> 4;

    const char* gA_h = (const char*)Ah + (size_t)m0 * 384;
    const char* gA_l = (const char*)Al + (size_t)m0 * 384;
    const char* gB   = (const char*)Bh + ((size_t)b * NPIX + n0) * 384;

    f32x4 acc[2][4];
    #pragma unroll
    for (int mf = 0; mf < 2; ++mf)
        #pragma unroll
        for (int nf = 0; nf < 4; ++nf)
            acc[mf][nf] = (f32x4){0.f, 0.f, 0.f, 0.f};

    for (int ks = 0; ks < 3; ++ks) {
        if (ks) __syncthreads();
        const int kb = ks * 128;
        #pragma unroll
        for (int it = 0; it < 2; ++it) {
            const int d  = it * 256 + tid;
            const int rd = d >> 3, cd = d & 7;
            const size_t src = (size_t)rd * 384 + kb + ((cd ^ (rd & 7)) << 4);
            cp16((char*)sAh + d * 16, gA_h + src);
            if (two) cp16((char*)sAl + d * 16, gA_l + src);
        }
        #pragma unroll
        for (int it = 0; it < 4; ++it) {
            const int d  = it * 256 + tid;
            const int rd = d >> 3, cd = d & 7;
            const size_t src = (size_t)rd * 384 + kb + ((cd ^ (rd & 7)) << 4);
            cp16((char*)sBh + d * 16, gB + src);
        }
        __syncthreads();
        #pragma unroll
        for (int s = 0; s < 2; ++s) {
            bf16x8 aH[2], aL[2], bH[4];
            #pragma unroll
            for (int mf = 0; mf < 2; ++mf) {
                const int row = wr * 32 + mf * 16 + lr;
                const int c = (s * 4 + kg) ^ (row & 7);
                aH[mf] = *(const bf16x8*)((const char*)sAh + row * 128 + c * 16);
                if (two) aL[mf] = *(const bf16x8*)((const char*)sAl + row * 128 + c * 16);
            }
            #pragma unroll
            for (int nf = 0; nf < 4; ++nf) {
                const int row = wc * 64 + nf * 16 + lr;
                const int c = (s * 4 + kg) ^ (row & 7);
                bH[nf] = *(const bf16x8*)((const char*)sBh + row * 128 + c * 16);
            }
            #pragma unroll
            for (int mf = 0; mf < 2; ++mf)
                #pragma unroll
                for (int nf = 0; nf < 4; ++nf) {
                    acc[mf][nf] = __builtin_amdgcn_mfma_f32_16x16x32_bf16(aH[mf], bH[nf], acc[mf][nf], 0, 0, 0);
                    if (two)
                        acc[mf][nf] = __builtin_amdgcn_mfma_f32_16x16x32_bf16(aL[mf], bH[nf], acc[mf][nf], 0, 0, 0);
                }
        }
    }

    if (MODE == 0) {
        float* Yb = (float*)Yv + ((size_t)b * M + m0 + wr * 32) * NPIX + n0 + wc * 64;
        #pragma unroll
        for (int mf = 0; mf < 2; ++mf)
            #pragma unroll
            for (int r = 0; r < 4; ++r) {
                const int row = mf * 16 + kg * 4 + r;
                #pragma unroll
                for (int nf = 0; nf < 4; ++nf)
                    Yb[(size_t)row * NPIX + nf * 16 + lr] = acc[mf][nf][r];
            }
    } else {
        #pragma unroll
        for (int mf = 0; mf < 2; ++mf) {
            const int cbase = m0 + wr * 32 + mf * 16 + kg * 4;
            unsigned* Yq = (unsigned*)Yv
                + (((size_t)b * 72 + (cbase >> 3)) * NPIX + n0 + wc * 64 + lr) * 4
                + ((kg & 1) << 1);
            #pragma unroll
            for (int nf = 0; nf < 4; ++nf) {
                Yq[(nf * 16) * 4 + 0] = packf16(acc[mf][nf][0], acc[mf][nf][1]);
                Yq[(nf * 16) * 4 + 1] = packf16(acc[mf][nf][2], acc[mf][nf][3]);
            }
        }
    }
}

// ---------------------------------------------------------------------------
// LDS-tiled neighborhood attention, f16 octet planes, pipelined staging.
// DB=true: double-buffered global_load_lds staging, counted vmcnt + raw
// s_barrier. DB=false (head (7,3)): classic syncthreads single-buffer.
// 8 rounds: r=0..3 QK octets, r=4..7 PV octets.
// ---------------------------------------------------------------------------
template<int KSZ, int DIL, bool DB, int L>
__device__ __forceinline__ void attn_body(
    const uint4* __restrict__ Qq, const uint4* __restrict__ Kq,
    const uint4* __restrict__ Vq, const float* __restrict__ bias,
    const uint4* __restrict__ guard,
    __bf16* __restrict__ oh, int h0, int w0,
    uint4* __restrict__ bufs,
    unsigned (* __restrict__ out_lds)[256])
{
    constexpr int CC  = KSZ / 2;
    constexpr int HAL = CC * DIL;
    constexpr int R   = 8 + 2 * HAL;
    constexpr int C   = 32 + 2 * HAL;
    constexpr int RC  = R * C;
    constexpr int NN  = KSZ * KSZ;

    const int tid = threadIdx.x;
    const int tx = tid & 31;
    const int ty = tid >> 5;
    const int pix = (h0 + ty) * WDIM + (w0 + tx);
    const int lb = ty * C + tx;

    // preload Q (all 4 octets): no VMEM loads inside the pipelined loop
    uint4 qv[4];
    #pragma unroll
    for (int p = 0; p < 4; ++p) qv[p] = Qq[(size_t)p * NPIX + pix];

    // bias folded into score init: e = exp2((dot + bias/scale) * scale*log2e)
    float score[NN];
    #pragma unroll
    for (int n = 0; n < NN; ++n) score[n] = bias[n] * 5.656854249492381f;

    auto STAGE = [&](int r) {
        const uint4* src = (r < 4) ? (Kq + (size_t)r * NPIX)
                                   : (Vq + (size_t)(r - 4) * NPIX);
        uint4* dst = bufs + (DB ? ((r & 1) * (L * 256)) : 0);
        #pragma unroll
        for (int it = 0; it < L; ++it) {
            const int idx = it * 256 + tid;
            const int rr = idx / C, cc = idx - rr * C;
            const int gh = h0 - HAL + rr, gw = w0 - HAL + cc;
            const bool ok = (idx < RC) && ((unsigned)gh < (unsigned)HDIM)
                                       && ((unsigned)gw < (unsigned)WDIM);
            const uint4* s = ok ? (src + gh * WDIM + gw) : guard;
            cp16(dst + idx, s);
        }
    };

    auto QK = [&](const uint4* buf, int oct) {
        const uint4 q = qv[oct];
        #pragma unroll
        for (int i = 0; i < KSZ; ++i)
            #pragma unroll
            for (int j = 0; j < KSZ; ++j) {
                const uint4 k8 = buf[lb + i * DIL * C + j * DIL];
                float s = score[i * KSZ + j];
                MIX_LL(s, k8.x, q.x); MIX_HH(s, k8.x, q.x);
                MIX_LL(s, k8.y, q.y); MIX_HH(s, k8.y, q.y);
                MIX_LL(s, k8.z, q.z); MIX_HH(s, k8.z, q.z);
                MIX_LL(s, k8.w, q.w); MIX_HH(s, k8.w, q.w);
                score[i * KSZ + j] = s;
            }
    };

    float inv = 0.f;
    auto SOFTMAX = [&]() {
        float l = 0.f;
        #pragma unroll
        for (int n = 0; n < NN; ++n) {
            // scale * log2(e) = 0.17677669529663689 * 1.4426950408889634
            const float e = exp2f(score[n] * 0.25506113952980654f);
            l += e;
            score[n] = e;
        }
        inv = 1.f / l;
    };

    auto PV = [&](const uint4* buf, int oct) {
        float a0 = 0.f, a1 = 0.f, a2 = 0.f, a3 = 0.f;
        float a4 = 0.f, a5 = 0.f, a6 = 0.f, a7 = 0.f;
        #pragma unroll
        for (int i = 0; i < KSZ; ++i)
            #pragma unroll
            for (int j = 0; j < KSZ; ++j) {
                const uint4 v8 = buf[lb + i * DIL * C + j * DIL];
                const float e = score[i * KSZ + j];
                MIX_LF(a0, v8.x, e); MIX_HF(a1, v8.x, e);
                MIX_LF(a2, v8.y, e); MIX_HF(a3, v8.y, e);
                MIX_LF(a4, v8.z, e); MIX_HF(a5, v8.z, e);
                MIX_LF(a6, v8.w, e); MIX_HF(a7, v8.w, e);
            }
        const int rr = oct & 1;
        const __bf16 c0 = (__bf16)(a0 * inv), c1 = (__bf16)(a1 * inv);
        const __bf16 c2 = (__bf16)(a2 * inv), c3 = (__bf16)(a3 * inv);
        const __bf16 c4 = (__bf16)(a4 * inv), c5 = (__bf16)(a5 * inv);
        const __bf16 c6 = (__bf16)(a6 * inv), c7 = (__bf16)(a7 * inv);
        out_lds[rr * 4 + 0][tid] = (unsigned)bfbits(c0) | ((unsigned)bfbits(c1) << 16);
        out_lds[rr * 4 + 1][tid] = (unsigned)bfbits(c2) | ((unsigned)bfbits(c3) << 16);
        out_lds[rr * 4 + 2][tid] = (unsigned)bfbits(c4) | ((unsigned)bfbits(c5) << 16);
        out_lds[rr * 4 + 3][tid] = (unsigned)bfbits(c6) | ((unsigned)bfbits(c7) << 16);
    };

    auto COOP = [&](int half) {     // coalesced half-record write (16 ch)
        #pragma unroll
        for (int it = 0; it < 2; ++it) {
            const int linear = it * 256 + tid;
            const int px = linear >> 1;
            const int c  = linear & 1;
            const int gpix = (h0 + (px >> 5)) * WDIM + w0 + (px & 31);
            uint4 val = make_uint4(out_lds[c * 4 + 0][px], out_lds[c * 4 + 1][px],
                                   out_lds[c * 4 + 2][px], out_lds[c * 4 + 3][px]);
            *((uint4*)((unsigned*)(oh + (size_t)gpix * 192)) + half * 2 + c) = val;
        }
    };

    if constexpr (DB) {
        STAGE(0);
        #pragma unroll
        for (int r = 0; r < 8; ++r) {
            if (r < 7) STAGE(r + 1);
            if (r < 7) waitcnt_vm<L>(); else waitcnt_vm<0>();  // stage(r) landed
            __builtin_amdgcn_s_barrier();
            __builtin_amdgcn_sched_barrier(0);
            const uint4* buf = bufs + (r & 1) * (L * 256);
            if (r < 4) {
                QK(buf, r);
                if (r == 3) SOFTMAX();
            } else {
                PV(buf, r - 4);
                asm volatile("s_waitcnt lgkmcnt(0)" ::: "memory");
                __builtin_amdgcn_sched_barrier(0);
            }
            __builtin_amdgcn_s_barrier();
            __builtin_amdgcn_sched_barrier(0);
            if (r == 5) COOP(0);
            if (r == 7) COOP(1);
        }
    } else {
        #pragma unroll
        for (int r = 0; r < 8; ++r) {
            __syncthreads();
            if (r == 6) COOP(0);
            STAGE(r);
            __syncthreads();
            const uint4* buf = bufs;
            if (r < 4) {
                QK(buf, r);
                if (r == 3) SOFTMAX();
            } else {
                PV(buf, r - 4);
            }
        }
        __syncthreads();
        COOP(1);
    }
}

// Flattened 864-block grid, XCD-chunked (3 panels per XCD: big/mid/small).
__global__ __launch_bounds__(256) void attn_kernel(
    const uint4* __restrict__ qkv, Bias6 bs, __bf16* __restrict__ ATh,
    const uint4* __restrict__ guard)
{
    __shared__ uint4 bufs[2560];             // 40 KB
    __shared__ unsigned out_lds[8][256];     // 8 KB

    const int orig = blockIdx.x;
    const int wg = (orig & 7) * 108 + (orig >> 3);
    const int panel = wg / 36;
    const int tile = wg - panel * 36;
    const int chunk = panel / 3, slot = panel - chunk * 3;
    int head, b;
    if (slot == 0)      { head = 4 + (chunk >> 2); b = chunk & 3; }
    else if (slot == 1) { head = 2 + (chunk >> 2); b = chunk & 3; }
    else                { head = (chunk < 4) ? 1 : 0; b = chunk & 3; }
    const int tx = tile % 3, ty = tile / 3;
    const int w0 = tx * 32, h0 = ty * 8;

    const uint4* base = qkv + (size_t)b * 72 * NPIX;
    const uint4* Qq = base + (size_t)(head * 4) * NPIX;
    const uint4* Kq = base + (size_t)(24 + head * 4) * NPIX;
    const uint4* Vq = base + (size_t)(48 + head * 4) * NPIX;
    __bf16* oh = ATh + (size_t)b * NPIX * 192 + head * 32;
    const float* bias = bs.p[head];

    switch (head) {
        case 0: attn_body<3, 1, true, 2>(Qq, Kq, Vq, bias, guard, oh, h0, w0, bufs, out_lds); break;
        case 1: attn_body<5, 2, true, 3>(Qq, Kq, Vq, bias, guard, oh, h0, w0, bufs, out_lds); break;
        case 2: attn_body<7, 1, true, 3>(Qq, Kq, Vq, bias, guard, oh, h0, w0, bufs, out_lds); break;
        case 3: attn_body<7, 3, false, 6>(Qq, Kq, Vq, bias, guard, oh, h0, w0, bufs, out_lds); break;
        case 4: attn_body<9, 1, true, 3>(Qq, Kq, Vq, bias, guard, oh, h0, w0, bufs, out_lds); break;
        case 5: attn_body<9, 2, true, 5>(Qq, Kq, Vq, bias, guard, oh, h0, w0, bufs, out_lds); break;
    }
}

// ---------------------------------------------------------------------------
extern "C" void kernel_launch(void* const* d_in, const int* in_sizes, int n_in,
                              void* d_out, int out_size, void* d_ws, size_t ws_size,
                              hipStream_t stream) {
    const float* x     = (const float*)d_in[0];   // [4][192][96][96]
    const float* w_qkv = (const float*)d_in[1];   // [576][192]
    const float* w_out = (const float*)d_in[2];   // [192][192]
    Bias6 bs;
    for (int i = 0; i < 6; ++i) bs.p[i] = (const float*)d_in[3 + i];
    float* out = (float*)d_out;                   // [4][192][96][96]

    char* ws = (char*)d_ws;
    uint4* QKV = (uint4*)ws;            ws += (size_t)BATCH * 72 * NPIX * 16;   // 42.5 MB
    __bf16* Xh  = (__bf16*)ws;          ws += (size_t)BATCH * NPIX * 192 * 2;   // 14.2 MB
    __bf16* ATh = (__bf16*)ws;          ws += (size_t)BATCH * NPIX * 192 * 2;   // 14.2 MB
    __bf16* W1h = (__bf16*)ws;          ws += (size_t)576 * 192 * 2;
    __bf16* W1l = (__bf16*)ws;          ws += (size_t)576 * 192 * 2;
    __bf16* W2h = (__bf16*)ws;          ws += (size_t)192 * 192 * 2;
    __bf16* W2l = (__bf16*)ws;          ws += (size_t)192 * 192 * 2;
    uint4* guard = (uint4*)ws;          ws += 1024;                              // zero page

    hipMemsetAsync(guard, 0, 1024, stream);

    // 1) x transpose+convert (+ inline weight conversion in one slice)
    convert_x<<<dim3(NPIX / 64, 192 / 32, BATCH), 256, 0, stream>>>(
        x, Xh, w_qkv, W1h, W1l, w_out, W2h, W2l);

    // 2) qkv projection (MFMA): f16 octet-planes; V rows 2-product, Q/K 1-product
    gemm_mfma<1, 384><<<dim3(NPIX / 128, 576 / 64, BATCH), 256, 0, stream>>>(
        W1h, W1l, Xh, (void*)QKV, 576);

    // 3) neighborhood attention -> bf16 records (coalesced)
    attn_kernel<<<dim3(864), 256, 0, stream>>>(QKV, bs, ATh, guard);

    // 4) out projection (MFMA, 1-product) -> d_out fp32 planes
    gemm_mfma<0, 1024><<<dim3(NPIX / 128, 192 / 64, BATCH), 256, 0, stream>>>(
        W2h, W2l, ATh, (void*)out, 192);
}

// Round 14
// 83.892 us; speedup vs baseline: 3.9278x; 1.0890x over previous
//
#include <hip/hip_runtime.h>
#include <hip/hip_bf16.h>
#include <math.h>

// Problem constants
#define NPIX 9216   // 96*96
#define HDIM 96
#define WDIM 96
#define NHEADS 6
#define BATCH 4

typedef _Float16 f16x8 __attribute__((ext_vector_type(8)));
typedef float    f32x4 __attribute__((ext_vector_type(4)));

struct Bias6 { const float* p[6]; };

// async global->LDS 16B copy (dest: wave-uniform base + lane*16)
__device__ __forceinline__ void cp16(void* ldst, const void* gsrc) {
    __builtin_amdgcn_global_load_lds(
        (const __attribute__((address_space(1))) unsigned int*)gsrc,
        (__attribute__((address_space(3))) unsigned int*)ldst, 16, 0, 0);
}

__device__ __forceinline__ unsigned packf16(float a, float b) {
    _Float16 ha = (_Float16)a, hb = (_Float16)b;
    return (unsigned)*(unsigned short*)&ha | ((unsigned)*(unsigned short*)&hb << 16);
}

template<int N>
__device__ __forceinline__ void waitcnt_vm() {
    if constexpr (N == 0) asm volatile("s_waitcnt vmcnt(0)" ::: "memory");
    else if constexpr (N == 2) asm volatile("s_waitcnt vmcnt(2)" ::: "memory");
    else if constexpr (N == 3) asm volatile("s_waitcnt vmcnt(3)" ::: "memory");
    else if constexpr (N == 5) asm volatile("s_waitcnt vmcnt(5)" ::: "memory");
    else asm volatile("s_waitcnt vmcnt(0)" ::: "memory");
    __builtin_amdgcn_sched_barrier(0);
}

// v_fma_mix_f32: acc += f16half(src0) * {f16half|f32}(src1), f32 accumulate.
#define MIX_LL(acc, kk, qq) asm("v_fma_mix_f32 %0, %1, %2, %0 op_sel:[0,0,0] op_sel_hi:[1,1,0]" : "+v"(acc) : "v"(kk), "v"(qq))
#define MIX_HH(acc, kk, qq) asm("v_fma_mix_f32 %0, %1, %2, %0 op_sel:[1,1,0] op_sel_hi:[1,1,0]" : "+v"(acc) : "v"(kk), "v"(qq))
#define MIX_LF(acc, vv, ee) asm("v_fma_mix_f32 %0, %1, %2, %0 op_sel:[0,0,0] op_sel_hi:[1,0,0]" : "+v"(acc) : "v"(vv), "v"(ee))
#define MIX_HF(acc, vv, ee) asm("v_fma_mix_f32 %0, %1, %2, %0 op_sel:[1,0,0] op_sel_hi:[1,0,0]" : "+v"(acc) : "v"(vv), "v"(ee))

// ---------------------------------------------------------------------------
// x transpose+convert: [B][192][NPIX] fp32 -> records [B][NPIX][192] f16.
// The y==0,z==0 block slice also converts both weight matrices to f16, and
// block (0,0,0) zeroes the OOB guard page.
// ---------------------------------------------------------------------------
__global__ __launch_bounds__(256) void convert_x(
    const float* __restrict__ x, _Float16* __restrict__ Xf,
    const float* __restrict__ w1, _Float16* __restrict__ Wf1,
    const float* __restrict__ w2, _Float16* __restrict__ Wf2,
    uint4* __restrict__ guard)
{
    __shared__ float t[32][65];
    const int b  = blockIdx.z;
    const int c0 = blockIdx.y * 32;
    const int p0 = blockIdx.x * 64;
    const int tid = threadIdx.x;

    if (blockIdx.y == 0 && blockIdx.z == 0) {
        const int f = blockIdx.x * 256 + tid;    // 0..36863
        #pragma unroll
        for (int u = 0; u < 4; ++u) {
            const int i = f * 4 + u;             // 0..147455
            if (i < 576 * 192) Wf1[i] = (_Float16)w1[i];
            else               Wf2[i - 576 * 192] = (_Float16)w2[i - 576 * 192];
        }
        if (blockIdx.x == 0 && tid < 64)
            guard[tid] = make_uint4(0u, 0u, 0u, 0u);
    }

    const int pl = tid & 63;
    #pragma unroll
    for (int i = 0; i < 8; ++i) {
        const int c = i * 4 + (tid >> 6);
        t[c][pl] = x[((size_t)b * 192 + c0 + c) * NPIX + p0 + pl];
    }
    __syncthreads();
    const int p  = tid >> 2;
    const int cq = (tid & 3) * 8;
    f16x8 vh;
    #pragma unroll
    for (int j = 0; j < 8; ++j)
        vh[j] = (_Float16)t[cq + j][p];
    *(f16x8*)(Xf + ((size_t)b * NPIX + p0 + p) * 192 + c0 + cq) = vh;
}

// ---------------------------------------------------------------------------
// f16 MFMA GEMM (1-product): Y[b][m][n] = sum_k W[m][k] * X[b][n][k]
// m97 structure: BM=64 BN=128 BK=64; global_load_lds staging + chunk-XOR swizzle.
// 1D grid, XCD-owned n-ranges: XCD x owns n-tiles [9x, 9x+9); within an XCD,
// m varies fastest so the 9x-reused B-records stay in that XCD's L2.
// MODE 0: Y float planes [B][M][NPIX] (final output).
// MODE 1: Y f16 channel-octet planes [B][M/8][NPIX] x uint4.
// ---------------------------------------------------------------------------
template<int MODE, int M>
__global__ __launch_bounds__(256) void gemm_mfma(
    const _Float16* __restrict__ A, const _Float16* __restrict__ B,
    void* __restrict__ Yv)
{
    constexpr int MT = M / 64;                  // m-tiles
    __shared__ _Float16 sA[64 * 64];            // 8 KB
    __shared__ _Float16 sB[128 * 64];           // 16 KB

    const int orig = blockIdx.x;
    const int xcd = orig & 7;
    const int l = orig >> 3;                    // 0 .. MT*4*9-1
    const int m0 = (l % MT) * 64;
    const int b  = (l / MT) & 3;
    const int n0 = (xcd * 9 + l / (MT * 4)) * 128;

    const int tid  = threadIdx.x;
    const int lane = tid & 63;
    const int wid  = tid >> 6;
    const int wr = wid >> 1, wc = wid & 1;
    const int lr = lane & 15;
    const int kg = lane >> 4;

    const char* gA = (const char*)A + (size_t)m0 * 384;
    const char* gB = (const char*)B + ((size_t)b * NPIX + n0) * 384;

    f32x4 acc[2][4];
    #pragma unroll
    for (int mf = 0; mf < 2; ++mf)
        #pragma unroll
        for (int nf = 0; nf < 4; ++nf)
            acc[mf][nf] = (f32x4){0.f, 0.f, 0.f, 0.f};

    for (int ks = 0; ks < 3; ++ks) {
        if (ks) __syncthreads();
        const int kb = ks * 128;
        #pragma unroll
        for (int it = 0; it < 2; ++it) {
            const int d  = it * 256 + tid;
            const int rd = d >> 3, cd = d & 7;
            const size_t src = (size_t)rd * 384 + kb + ((cd ^ (rd & 7)) << 4);
            cp16((char*)sA + d * 16, gA + src);
        }
        #pragma unroll
        for (int it = 0; it < 4; ++it) {
            const int d  = it * 256 + tid;
            const int rd = d >> 3, cd = d & 7;
            const size_t src = (size_t)rd * 384 + kb + ((cd ^ (rd & 7)) << 4);
            cp16((char*)sB + d * 16, gB + src);
        }
        __syncthreads();
        #pragma unroll
        for (int s = 0; s < 2; ++s) {
            f16x8 aH[2], bH[4];
            #pragma unroll
            for (int mf = 0; mf < 2; ++mf) {
                const int row = wr * 32 + mf * 16 + lr;
                const int c = (s * 4 + kg) ^ (row & 7);
                aH[mf] = *(const f16x8*)((const char*)sA + row * 128 + c * 16);
            }
            #pragma unroll
            for (int nf = 0; nf < 4; ++nf) {
                const int row = wc * 64 + nf * 16 + lr;
                const int c = (s * 4 + kg) ^ (row & 7);
                bH[nf] = *(const f16x8*)((const char*)sB + row * 128 + c * 16);
            }
            #pragma unroll
            for (int mf = 0; mf < 2; ++mf)
                #pragma unroll
                for (int nf = 0; nf < 4; ++nf)
                    acc[mf][nf] = __builtin_amdgcn_mfma_f32_16x16x32_f16(aH[mf], bH[nf], acc[mf][nf], 0, 0, 0);
        }
    }

    // D layout: col = lane&15, row = (lane>>4)*4 + r
    if (MODE == 0) {
        float* Yb = (float*)Yv + ((size_t)b * M + m0 + wr * 32) * NPIX + n0 + wc * 64;
        #pragma unroll
        for (int mf = 0; mf < 2; ++mf)
            #pragma unroll
            for (int r = 0; r < 4; ++r) {
                const int row = mf * 16 + kg * 4 + r;
                #pragma unroll
                for (int nf = 0; nf < 4; ++nf)
                    Yb[(size_t)row * NPIX + nf * 16 + lr] = acc[mf][nf][r];
            }
    } else {
        #pragma unroll
        for (int mf = 0; mf < 2; ++mf) {
            const int cbase = m0 + wr * 32 + mf * 16 + kg * 4;
            unsigned* Yq = (unsigned*)Yv
                + (((size_t)b * 72 + (cbase >> 3)) * NPIX + n0 + wc * 64 + lr) * 4
                + ((kg & 1) << 1);
            #pragma unroll
            for (int nf = 0; nf < 4; ++nf) {
                Yq[(nf * 16) * 4 + 0] = packf16(acc[mf][nf][0], acc[mf][nf][1]);
                Yq[(nf * 16) * 4 + 1] = packf16(acc[mf][nf][2], acc[mf][nf][3]);
            }
        }
    }
}

// ---------------------------------------------------------------------------
// LDS-tiled neighborhood attention, f16 octet planes.
// DB=true: double-buffered staging, counted vmcnt + raw s_barrier.
// DB=false (heads (7,3),(9,2): region too big for 2 buffers in 24KB):
// syncthreads single-buffer; 5 blocks/CU gives cross-block overlap instead.
// 8 rounds: r=0..3 QK octets, r=4..7 PV octets. Output f16 records.
// ---------------------------------------------------------------------------
template<int KSZ, int DIL, bool DB, int L>
__device__ __forceinline__ void attn_body(
    const uint4* __restrict__ Qq, const uint4* __restrict__ Kq,
    const uint4* __restrict__ Vq, const float* __restrict__ bias,
    const uint4* __restrict__ guard,
    _Float16* __restrict__ oh, int h0, int w0,
    uint4* __restrict__ bufs,
    unsigned (* __restrict__ out_lds)[256])
{
    constexpr int CC  = KSZ / 2;
    constexpr int HAL = CC * DIL;
    constexpr int R   = 8 + 2 * HAL;
    constexpr int C   = 32 + 2 * HAL;
    constexpr int RC  = R * C;
    constexpr int NN  = KSZ * KSZ;

    const int tid = threadIdx.x;
    const int tx = tid & 31;
    const int ty = tid >> 5;
    const int pix = (h0 + ty) * WDIM + (w0 + tx);
    const int lb = ty * C + tx;

    uint4 qv[4];
    #pragma unroll
    for (int p = 0; p < 4; ++p) qv[p] = Qq[(size_t)p * NPIX + pix];

    // bias folded into score init: e = exp2((dot + bias/scale) * scale*log2e)
    float score[NN];
    #pragma unroll
    for (int n = 0; n < NN; ++n) score[n] = bias[n] * 5.656854249492381f;

    auto STAGE = [&](int r) {
        const uint4* src = (r < 4) ? (Kq + (size_t)r * NPIX)
                                   : (Vq + (size_t)(r - 4) * NPIX);
        uint4* dst = bufs + (DB ? ((r & 1) * (L * 256)) : 0);
        #pragma unroll
        for (int it = 0; it < L; ++it) {
            const int idx = it * 256 + tid;
            const int rr = idx / C, cc = idx - rr * C;
            const int gh = h0 - HAL + rr, gw = w0 - HAL + cc;
            const bool ok = (idx < RC) && ((unsigned)gh < (unsigned)HDIM)
                                       && ((unsigned)gw < (unsigned)WDIM);
            const uint4* s = ok ? (src + gh * WDIM + gw) : guard;
            cp16(dst + idx, s);
        }
    };

    auto QK = [&](const uint4* buf, int oct) {
        const uint4 q = qv[oct];
        #pragma unroll
        for (int i = 0; i < KSZ; ++i)
            #pragma unroll
            for (int j = 0; j < KSZ; ++j) {
                const uint4 k8 = buf[lb + i * DIL * C + j * DIL];
                float s = score[i * KSZ + j];
                MIX_LL(s, k8.x, q.x); MIX_HH(s, k8.x, q.x);
                MIX_LL(s, k8.y, q.y); MIX_HH(s, k8.y, q.y);
                MIX_LL(s, k8.z, q.z); MIX_HH(s, k8.z, q.z);
                MIX_LL(s, k8.w, q.w); MIX_HH(s, k8.w, q.w);
                score[i * KSZ + j] = s;
            }
    };

    float inv = 0.f;
    auto SOFTMAX = [&]() {
        float l = 0.f;
        #pragma unroll
        for (int n = 0; n < NN; ++n) {
            // scale * log2(e)
            const float e = exp2f(score[n] * 0.25506113952980654f);
            l += e;
            score[n] = e;
        }
        inv = 1.f / l;
    };

    auto PV = [&](const uint4* buf, int oct) {
        float a0 = 0.f, a1 = 0.f, a2 = 0.f, a3 = 0.f;
        float a4 = 0.f, a5 = 0.f, a6 = 0.f, a7 = 0.f;
        #pragma unroll
        for (int i = 0; i < KSZ; ++i)
            #pragma unroll
            for (int j = 0; j < KSZ; ++j) {
                const uint4 v8 = buf[lb + i * DIL * C + j * DIL];
                const float e = score[i * KSZ + j];
                MIX_LF(a0, v8.x, e); MIX_HF(a1, v8.x, e);
                MIX_LF(a2, v8.y, e); MIX_HF(a3, v8.y, e);
                MIX_LF(a4, v8.z, e); MIX_HF(a5, v8.z, e);
                MIX_LF(a6, v8.w, e); MIX_HF(a7, v8.w, e);
            }
        const int rr = oct & 1;
        out_lds[rr * 4 + 0][tid] = packf16(a0 * inv, a1 * inv);
        out_lds[rr * 4 + 1][tid] = packf16(a2 * inv, a3 * inv);
        out_lds[rr * 4 + 2][tid] = packf16(a4 * inv, a5 * inv);
        out_lds[rr * 4 + 3][tid] = packf16(a6 * inv, a7 * inv);
    };

    auto COOP = [&](int half) {     // coalesced half-record write (16 ch)
        #pragma unroll
        for (int it = 0; it < 2; ++it) {
            const int linear = it * 256 + tid;
            const int px = linear >> 1;
            const int c  = linear & 1;
            const int gpix = (h0 + (px >> 5)) * WDIM + w0 + (px & 31);
            uint4 val = make_uint4(out_lds[c * 4 + 0][px], out_lds[c * 4 + 1][px],
                                   out_lds[c * 4 + 2][px], out_lds[c * 4 + 3][px]);
            *((uint4*)((unsigned*)(oh + (size_t)gpix * 192)) + half * 2 + c) = val;
        }
    };

    if constexpr (DB) {
        STAGE(0);
        #pragma unroll
        for (int r = 0; r < 8; ++r) {
            if (r < 7) STAGE(r + 1);
            if (r < 7) waitcnt_vm<L>(); else waitcnt_vm<0>();
            __builtin_amdgcn_s_barrier();
            __builtin_amdgcn_sched_barrier(0);
            const uint4* buf = bufs + (r & 1) * (L * 256);
            if (r < 4) {
                QK(buf, r);
                if (r == 3) SOFTMAX();
            } else {
                PV(buf, r - 4);
                asm volatile("s_waitcnt lgkmcnt(0)" ::: "memory");
                __builtin_amdgcn_sched_barrier(0);
            }
            __builtin_amdgcn_s_barrier();
            __builtin_amdgcn_sched_barrier(0);
            if (r == 5) COOP(0);
            if (r == 7) COOP(1);
        }
    } else {
        #pragma unroll
        for (int r = 0; r < 8; ++r) {
            __syncthreads();
            if (r == 6) COOP(0);
            STAGE(r);
            __syncthreads();
            const uint4* buf = bufs;
            if (r < 4) {
                QK(buf, r);
                if (r == 3) SOFTMAX();
            } else {
                PV(buf, r - 4);
            }
        }
        __syncthreads();
        COOP(1);
    }
}

// Flattened 864-block grid, XCD-chunked (3 panels per XCD: big/mid/small).
__global__ __launch_bounds__(256) void attn_kernel(
    const uint4* __restrict__ qkv, Bias6 bs, _Float16* __restrict__ ATf,
    const uint4* __restrict__ guard)
{
    __shared__ uint4 bufs[1536];             // 24 KB (worst head (7,3) L=6)
    __shared__ unsigned out_lds[8][256];     // 8 KB  -> 32 KB total, 5 blk/CU

    const int orig = blockIdx.x;
    const int wg = (orig & 7) * 108 + (orig >> 3);
    const int panel = wg / 36;
    const int tile = wg - panel * 36;
    const int chunk = panel / 3, slot = panel - chunk * 3;
    int head, b;
    if (slot == 0)      { head = 4 + (chunk >> 2); b = chunk & 3; }
    else if (slot == 1) { head = 2 + (chunk >> 2); b = chunk & 3; }
    else                { head = (chunk < 4) ? 1 : 0; b = chunk & 3; }
    const int tx = tile % 3, ty = tile / 3;
    const int w0 = tx * 32, h0 = ty * 8;

    const uint4* base = qkv + (size_t)b * 72 * NPIX;
    const uint4* Qq = base + (size_t)(head * 4) * NPIX;
    const uint4* Kq = base + (size_t)(24 + head * 4) * NPIX;
    const uint4* Vq = base + (size_t)(48 + head * 4) * NPIX;
    _Float16* oh = ATf + (size_t)b * NPIX * 192 + head * 32;
    const float* bias = bs.p[head];

    switch (head) {
        case 0: attn_body<3, 1, true, 2>(Qq, Kq, Vq, bias, guard, oh, h0, w0, bufs, out_lds); break;
        case 1: attn_body<5, 2, true, 3>(Qq, Kq, Vq, bias, guard, oh, h0, w0, bufs, out_lds); break;
        case 2: attn_body<7, 1, true, 3>(Qq, Kq, Vq, bias, guard, oh, h0, w0, bufs, out_lds); break;
        case 3: attn_body<7, 3, false, 6>(Qq, Kq, Vq, bias, guard, oh, h0, w0, bufs, out_lds); break;
        case 4: attn_body<9, 1, true, 3>(Qq, Kq, Vq, bias, guard, oh, h0, w0, bufs, out_lds); break;
        case 5: attn_body<9, 2, false, 5>(Qq, Kq, Vq, bias, guard, oh, h0, w0, bufs, out_lds); break;
    }
}

// ---------------------------------------------------------------------------
extern "C" void kernel_launch(void* const* d_in, const int* in_sizes, int n_in,
                              void* d_out, int out_size, void* d_ws, size_t ws_size,
                              hipStream_t stream) {
    const float* x     = (const float*)d_in[0];   // [4][192][96][96]
    const float* w_qkv = (const float*)d_in[1];   // [576][192]
    const float* w_out = (const float*)d_in[2];   // [192][192]
    Bias6 bs;
    for (int i = 0; i < 6; ++i) bs.p[i] = (const float*)d_in[3 + i];
    float* out = (float*)d_out;                   // [4][192][96][96]

    char* ws = (char*)d_ws;
    uint4*    QKV = (uint4*)ws;         ws += (size_t)BATCH * 72 * NPIX * 16;   // 42.5 MB
    _Float16* Xf  = (_Float16*)ws;      ws += (size_t)BATCH * NPIX * 192 * 2;   // 14.2 MB
    _Float16* ATf = (_Float16*)ws;      ws += (size_t)BATCH * NPIX * 192 * 2;   // 14.2 MB
    _Float16* Wf1 = (_Float16*)ws;      ws += (size_t)576 * 192 * 2;
    _Float16* Wf2 = (_Float16*)ws;      ws += (size_t)192 * 192 * 2;
    uint4* guard  = (uint4*)ws;         ws += 1024;                              // zero page

    // 1) x transpose+convert to f16 records (+ weight convert + guard zero)
    convert_x<<<dim3(NPIX / 64, 192 / 32, BATCH), 256, 0, stream>>>(
        x, Xf, w_qkv, Wf1, w_out, Wf2, guard);

    // 2) qkv projection (f16 MFMA) -> f16 octet-planes [B][72][NPIX] x uint4
    gemm_mfma<1, 576><<<dim3(8 * (576 / 64) * 4 * 9), 256, 0, stream>>>(
        Wf1, Xf, (void*)QKV);

    // 3) neighborhood attention -> f16 records (coalesced)
    attn_kernel<<<dim3(864), 256, 0, stream>>>(QKV, bs, ATf, guard);

    // 4) out projection (f16 MFMA) -> d_out fp32 planes
    gemm_mfma<0, 192><<<dim3(8 * (192 / 64) * 4 * 9), 256, 0, stream>>>(
        Wf2, ATf, (void*)out);
}